// Round 1
// baseline (629.077 us; speedup 1.0000x reference)
//
#include <hip/hip_runtime.h>
#include <hip/hip_bf16.h>
#include <float.h>

#define EDIM 128
#define NFACT 4096
#define NENT 2048
#define BQ 8
#define KTOP 10

__device__ __forceinline__ float wave_sum(float v) {
#pragma unroll
    for (int m = 32; m; m >>= 1) v += __shfl_xor(v, m, 64);
    return v;
}

// ---------------- init: msum = FLT_MAX, base_min = FLT_MAX -------------
__global__ void k_init(float* msum, float* base_min) {
    int i = blockIdx.x * blockDim.x + threadIdx.x;
    const int total = 16 * NENT;
    for (; i < total; i += gridDim.x * blockDim.x) msum[i] = FLT_MAX;
    if (blockIdx.x == 0 && threadIdx.x < BQ) base_min[threadIdx.x] = FLT_MAX;
}

// ---------------- hops: h[(r*2+jj)*8+b][e] = rel[b] @ W[r][jj] + bias --
__global__ void k_hops(const float* __restrict__ rel, const float* __restrict__ W,
                       const float* __restrict__ bias, float* __restrict__ h) {
    int gt = blockIdx.x * 256 + threadIdx.x;   // 0..4095
    int e = gt & 127;
    int idx = gt >> 7;                         // (r*2+jj)*8 + b, 0..31
    int b = idx & 7;
    int rj = idx >> 3;                         // 0..3
    const float* Wp = W + rj * EDIM * EDIM;    // [k][e]
    float acc = bias[rj * EDIM + e];
    for (int k = 0; k < EDIM; ++k)
        acc += rel[b * EDIM + k] * Wp[k * EDIM + e];
    h[idx * EDIM + e] = acc;
}

// ---------------- query norms, 56 vectors ------------------------------
// order: 0..7 rel[b], 8..15 arg1[b], 16..23 arg2[b], 24..39 h1[r][b], 40..55 h2[r][b]
__global__ void k_qnorm(const float* __restrict__ rel, const float* __restrict__ a1,
                        const float* __restrict__ a2, const float* __restrict__ h,
                        float* __restrict__ qn) {
    int j = blockIdx.x;
    int l = threadIdx.x;
    const float* v;
    if (j < 8) v = rel + j * EDIM;
    else if (j < 16) v = a1 + (j - 8) * EDIM;
    else if (j < 24) v = a2 + (j - 16) * EDIM;
    else {
        int t = j - 24;                 // 0..31
        int jj = t >> 4;                // 0 = h1, 1 = h2
        int r = (t >> 3) & 1;
        int b = t & 7;
        v = h + ((r * 2 + jj) * 8 + b) * EDIM;
    }
    float p = v[l] * v[l] + v[l + 64] * v[l + 64];
    p = wave_sum(p);
    if (l == 0) qn[j] = p;
}

// ---------------- entity norms -----------------------------------------
__global__ void k_ne(const float* __restrict__ ent, float* __restrict__ ne) {
    int gt = blockIdx.x * blockDim.x + threadIdx.x;
    int wid = gt >> 6, lane = gt & 63;
    int nw = (gridDim.x * blockDim.x) >> 6;
    for (int n = wid; n < NENT; n += nw) {
        float a = ent[n * EDIM + lane];
        float b = ent[n * EDIM + lane + 64];
        float p = wave_sum(a * a + b * b);
        if (lane == 0) ne[n] = p;
    }
}

// ---------------- dots: 7 groups of 8 query rows vs facts --------------
// group g: 0 rel.fr, 1 h1r0.fr, 2 h1r1.fr, 3 h2r0.fr, 4 h2r1.fr, 5 arg1.fs, 6 arg2.fo
// dots[(g*8+j)*NFACT + f]; also writes fact norms nfr/nfs/nfo.
__global__ void k_dots(const float* __restrict__ rel, const float* __restrict__ a1,
                       const float* __restrict__ a2, const float* __restrict__ h,
                       const float* __restrict__ fr, const float* __restrict__ fs,
                       const float* __restrict__ fo, float* __restrict__ dots,
                       float* __restrict__ nfr, float* __restrict__ nfs,
                       float* __restrict__ nfo) {
    __shared__ __align__(16) float q[128 * 64];   // [e][j], j padded to 64
    for (int idx = threadIdx.x; idx < 128 * 64; idx += 256) {
        int e = idx >> 6, j = idx & 63;
        float v = 0.f;
        if (j < 56) {
            if (j < 8) v = rel[j * 128 + e];
            else if (j < 16) v = a1[(j - 8) * 128 + e];
            else if (j < 24) v = a2[(j - 16) * 128 + e];
            else {
                int t2 = j - 24;
                int jj = t2 >> 4, r = (t2 >> 3) & 1, bb = t2 & 7;
                v = h[((r * 2 + jj) * 8 + bb) * 128 + e];
            }
        }
        q[idx] = v;
    }
    __syncthreads();

    int tg = blockIdx.x * 256 + threadIdx.x;      // 0..28671
    int f = tg & (NFACT - 1);
    int g = tg >> 12;                             // 0..6
    const float* rowp = ((g < 5) ? fr : (g == 5 ? fs : fo)) + f * EDIM;
    const int qbase_tab[7] = {0, 24, 32, 40, 48, 8, 16};
    int qb = qbase_tab[g];

    float acc[8] = {0, 0, 0, 0, 0, 0, 0, 0};
    float nrm = 0.f;
    const float4* rp4 = (const float4*)rowp;
#pragma unroll 4
    for (int es = 0; es < 32; ++es) {
        float4 x = rp4[es];
        float xs[4] = {x.x, x.y, x.z, x.w};
        nrm += x.x * x.x + x.y * x.y + x.z * x.z + x.w * x.w;
#pragma unroll
        for (int c = 0; c < 4; ++c) {
            int e = es * 4 + c;
            float xe = xs[c];
            float4 q0 = *(const float4*)&q[e * 64 + qb];
            float4 q1 = *(const float4*)&q[e * 64 + qb + 4];
            acc[0] += xe * q0.x; acc[1] += xe * q0.y;
            acc[2] += xe * q0.z; acc[3] += xe * q0.w;
            acc[4] += xe * q1.x; acc[5] += xe * q1.y;
            acc[6] += xe * q1.z; acc[7] += xe * q1.w;
        }
    }
#pragma unroll
    for (int j = 0; j < 8; ++j) dots[(g * 8 + j) * NFACT + f] = acc[j];
    if (g == 0) nfr[f] = nrm;
    else if (g == 5) nfs[f] = nrm;
    else if (g == 6) nfo[f] = nrm;
}

// ---------------- combine dots -> c1, qh2, qa2, base_min ---------------
__global__ void k_combine(const float* __restrict__ dots, const float* __restrict__ qn,
                          const float* __restrict__ nfr, const float* __restrict__ nfs,
                          const float* __restrict__ nfo, float* __restrict__ c1,
                          float* __restrict__ qh2, float* __restrict__ qa2,
                          float* __restrict__ base_min) {
    __shared__ unsigned sbase;
    if (threadIdx.x == 0) sbase = 0x7f7fffffu;    // FLT_MAX bits
    __syncthreads();
    int gid = blockIdx.x * 256 + threadIdx.x;     // 0..32767
    int b = gid >> 12;
    int f = gid & (NFACT - 1);
    float nfrf = nfr[f], nfsf = nfs[f], nfof = nfo[f];
    float qa1v = fmaxf(qn[8 + b] + nfsf - 2.f * dots[(5 * 8 + b) * NFACT + f], 0.f);
    float qa2v = fmaxf(qn[16 + b] + nfof - 2.f * dots[(6 * 8 + b) * NFACT + f], 0.f);
    qa2[b * NFACT + f] = qa2v;
    float cb = fmaxf(qn[b] + nfrf - 2.f * dots[(0 * 8 + b) * NFACT + f], 0.f) + qa1v + qa2v;
#pragma unroll
    for (int r = 0; r < 2; ++r) {
        float t1 = fmaxf(qn[24 + r * 8 + b] + nfrf - 2.f * dots[((1 + r) * 8 + b) * NFACT + f], 0.f);
        c1[(r * 8 + b) * NFACT + f] = t1 + qa1v;
        qh2[(r * 8 + b) * NFACT + f] =
            fmaxf(qn[40 + r * 8 + b] + nfrf - 2.f * dots[((3 + r) * 8 + b) * NFACT + f], 0.f);
    }
    atomicMin(&sbase, __float_as_uint(cb));
    __syncthreads();
    if (threadIdx.x == 0) atomicMin((unsigned*)&base_min[b], sbase);
}

// ---------------- fused ent x fo GEMM + min-plus -----------------------
// block: 64 entities x 512-fact slice, inner tiles of 32 facts.
__global__ __launch_bounds__(256) void k_minplus(
        const float* __restrict__ ent, const float* __restrict__ fo,
        const float* __restrict__ ne, const float* __restrict__ nfo,
        const float* __restrict__ c1, float* __restrict__ msum) {
    __shared__ __align__(16) float ent_l[64 * 132];
    __shared__ __align__(16) float fo_l[32 * 132];
    __shared__ float d_l[64 * 33];
    __shared__ float c_l[16 * 32];
    __shared__ float ne_l[64];
    __shared__ float nfo_l[32];
    int tid = threadIdx.x;
    int nb = blockIdx.x * 64;
    int fs0 = blockIdx.y * 512;

    for (int idx = tid; idx < 64 * 128; idx += 256) {
        int row = idx >> 7, col = idx & 127;
        ent_l[row * 132 + col] = ent[(nb + row) * EDIM + col];
    }
    if (tid < 64) ne_l[tid] = ne[nb + tid];

    int ng = tid & 15, fg = tid >> 4;     // gemm: rows ng+16i, cols fg+16j
    int en = tid & 63, brg = tid >> 6;    // epilogue: entity en, br group
    float m[4] = {FLT_MAX, FLT_MAX, FLT_MAX, FLT_MAX};

    for (int ci = 0; ci < 16; ++ci) {
        int fb = fs0 + ci * 32;
        __syncthreads();   // staging vs previous epilogue readers (and initial ent stage)
        for (int idx = tid; idx < 32 * 128; idx += 256) {
            int row = idx >> 7, col = idx & 127;
            fo_l[row * 132 + col] = fo[(fb + row) * EDIM + col];
        }
        if (tid < 32) nfo_l[tid] = nfo[fb + tid];
        for (int idx = tid; idx < 512; idx += 256) {
            int row = idx >> 5, col = idx & 31;
            c_l[idx] = c1[row * NFACT + fb + col];
        }
        __syncthreads();

        float acc[4][2];
#pragma unroll
        for (int i = 0; i < 4; ++i) { acc[i][0] = 0.f; acc[i][1] = 0.f; }
#pragma unroll 4
        for (int es = 0; es < 32; ++es) {
            float4 bv0 = *(const float4*)&fo_l[fg * 132 + es * 4];
            float4 bv1 = *(const float4*)&fo_l[(fg + 16) * 132 + es * 4];
#pragma unroll
            for (int i = 0; i < 4; ++i) {
                float4 av = *(const float4*)&ent_l[(ng + 16 * i) * 132 + es * 4];
                acc[i][0] += av.x * bv0.x + av.y * bv0.y + av.z * bv0.z + av.w * bv0.w;
                acc[i][1] += av.x * bv1.x + av.y * bv1.y + av.z * bv1.z + av.w * bv1.w;
            }
        }
#pragma unroll
        for (int i = 0; i < 4; ++i)
#pragma unroll
            for (int j = 0; j < 2; ++j)
                d_l[(ng + 16 * i) * 33 + fg + 16 * j] =
                    fmaxf(ne_l[ng + 16 * i] + nfo_l[fg + 16 * j] - 2.f * acc[i][j], 0.f);
        __syncthreads();

        for (int f = 0; f < 32; ++f) {
            float dv = d_l[en * 33 + f];
#pragma unroll
            for (int q = 0; q < 4; ++q)
                m[q] = fminf(m[q], c_l[(brg * 4 + q) * 32 + f] + dv);
        }
    }
#pragma unroll
    for (int q = 0; q < 4; ++q)
        atomicMin((unsigned*)&msum[(brg * 4 + q) * NENT + nb + en], __float_as_uint(m[q]));
}

// ---------------- top-10 smallest msum per (r,b) row -------------------
__global__ void k_topk(const float* __restrict__ msum, int* __restrict__ z_idx,
                       float* __restrict__ z_msum) {
    __shared__ float sv[NENT];
    __shared__ float rv[256];
    __shared__ int ri[256];
    int br = blockIdx.x, t = threadIdx.x;
    for (int i = t; i < NENT; i += 256) sv[i] = msum[br * NENT + i];
    __syncthreads();
    for (int it = 0; it < KTOP; ++it) {
        float best = FLT_MAX;
        int bi = 1 << 30;
        for (int i = t; i < NENT; i += 256) {
            float v = sv[i];
            if (v < best || (v == best && i < bi)) { best = v; bi = i; }
        }
        rv[t] = best; ri[t] = bi;
        __syncthreads();
        for (int s = 128; s > 0; s >>= 1) {
            if (t < s) {
                float ov = rv[t + s]; int oi = ri[t + s];
                if (ov < rv[t] || (ov == rv[t] && oi < ri[t])) { rv[t] = ov; ri[t] = oi; }
            }
            __syncthreads();
        }
        if (t == 0) {
            z_idx[br * KTOP + it] = ri[0];
            z_msum[br * KTOP + it] = rv[0];
            sv[ri[0]] = FLT_MAX;
        }
        __syncthreads();
    }
}

// ---------------- z2: min over facts of qh2 + clamp(z,fs) + qa2 --------
__global__ void k_z2(const float* __restrict__ ent, const float* __restrict__ fs,
                     const float* __restrict__ nfs, const float* __restrict__ qh2,
                     const float* __restrict__ qa2, const int* __restrict__ z_idx,
                     float* __restrict__ z2sum) {
    __shared__ float sz[128];
    __shared__ float wmin_s[4];
    int bid = blockIdx.x;          // br*10 + k
    int br = bid / KTOP;
    int b = br & 7;
    int t = threadIdx.x, lane = t & 63, wid = t >> 6;
    int n = z_idx[bid];
    if (t < 128) sz[t] = ent[n * EDIM + t];
    __syncthreads();
    float z0 = sz[lane], z1 = sz[lane + 64];
    float nz = wave_sum(z0 * z0 + z1 * z1);
    const float* qh2r = qh2 + br * NFACT;
    const float* qa2r = qa2 + b * NFACT;
    float wmin = FLT_MAX;
    for (int f = wid; f < NFACT; f += 4) {
        float p = z0 * fs[f * EDIM + lane] + z1 * fs[f * EDIM + lane + 64];
        p = wave_sum(p);
        float val = qh2r[f] + fmaxf(nz + nfs[f] - 2.f * p, 0.f) + qa2r[f];
        wmin = fminf(wmin, val);
    }
    if (lane == 0) wmin_s[wid] = wmin;
    __syncthreads();
    if (t == 0)
        z2sum[bid] = fminf(fminf(wmin_s[0], wmin_s[1]), fminf(wmin_s[2], wmin_s[3]));
}

// ---------------- final combine ----------------------------------------
__global__ void k_final(const float* __restrict__ base_min, const float* __restrict__ z_msum,
                        const float* __restrict__ z2sum, float* __restrict__ out) {
    int b = threadIdx.x;
    if (b >= BQ) return;
    float best = expf(-0.5f * base_min[b]);
#pragma unroll
    for (int r = 0; r < 2; ++r) {
        int br = r * 8 + b;
        float rb = 0.f;
        for (int k = 0; k < KTOP; ++k) {
            float s = expf(-0.5f * fmaxf(z2sum[br * KTOP + k], z_msum[br * KTOP + k]));
            rb = fmaxf(rb, s);
        }
        best = fmaxf(best, rb);
    }
    out[b] = best;
}

extern "C" void kernel_launch(void* const* d_in, const int* in_sizes, int n_in,
                              void* d_out, int out_size, void* d_ws, size_t ws_size,
                              hipStream_t stream) {
    const float* rel = (const float*)d_in[0];
    const float* arg1 = (const float*)d_in[1];
    const float* arg2 = (const float*)d_in[2];
    const float* fr = (const float*)d_in[3];
    const float* fs = (const float*)d_in[4];
    const float* fo = (const float*)d_in[5];
    const float* ent = (const float*)d_in[6];
    const float* W = (const float*)d_in[7];
    const float* bias = (const float*)d_in[8];
    float* out = (float*)d_out;

    float* w = (float*)d_ws;
    float* h = w;                          // 4096
    float* qn = h + 4096;                  // 64
    float* nfr = qn + 64;                  // 4096
    float* nfs = nfr + 4096;               // 4096
    float* nfo = nfs + 4096;               // 4096
    float* ne = nfo + 4096;                // 2048
    float* dots = ne + 2048;               // 7*8*4096 = 229376
    float* c1 = dots + 229376;             // 16*4096 = 65536
    float* qh2 = c1 + 65536;               // 65536
    float* qa2 = qh2 + 65536;              // 8*4096 = 32768
    float* msum = qa2 + 32768;             // 16*2048 = 32768
    float* base_min = msum + 32768;        // 8
    float* z_msum = base_min + 8;          // 160
    float* z2sum = z_msum + 160;           // 160
    int* z_idx = (int*)(z2sum + 160);      // 160

    k_init<<<64, 256, 0, stream>>>(msum, base_min);
    k_hops<<<16, 256, 0, stream>>>(rel, W, bias, h);
    k_qnorm<<<56, 64, 0, stream>>>(rel, arg1, arg2, h, qn);
    k_ne<<<8, 256, 0, stream>>>(ent, ne);
    k_dots<<<112, 256, 0, stream>>>(rel, arg1, arg2, h, fr, fs, fo, dots, nfr, nfs, nfo);
    k_combine<<<128, 256, 0, stream>>>(dots, qn, nfr, nfs, nfo, c1, qh2, qa2, base_min);
    k_minplus<<<dim3(32, 8), 256, 0, stream>>>(ent, fo, ne, nfo, c1, msum);
    k_topk<<<16, 256, 0, stream>>>(msum, z_idx, z_msum);
    k_z2<<<160, 256, 0, stream>>>(ent, fs, nfs, qh2, qa2, z_idx, z2sum);
    k_final<<<1, 64, 0, stream>>>(base_min, z_msum, z2sum, out);
}

// Round 2
// 232.424 us; speedup vs baseline: 2.7066x; 2.7066x over previous
//
#include <hip/hip_runtime.h>
#include <hip/hip_bf16.h>
#include <float.h>

#define EDIM 128
#define NFACT 4096
#define NENT 2048
#define BQ 8
#define KTOP 10

__device__ __forceinline__ float wave_sum(float v) {
#pragma unroll
    for (int m = 32; m; m >>= 1) v += __shfl_xor(v, m, 64);
    return v;
}

// ---------------- init: msum/base_min/z2sum = FLT_MAX ------------------
__global__ void k_init(float* msum, float* base_min, float* z2sum) {
    int i = blockIdx.x * blockDim.x + threadIdx.x;
    const int total = 16 * NENT;
    for (; i < total; i += gridDim.x * blockDim.x) msum[i] = FLT_MAX;
    if (blockIdx.x == 0 && threadIdx.x < BQ) base_min[threadIdx.x] = FLT_MAX;
    if (blockIdx.x == 1 && threadIdx.x < 160) z2sum[threadIdx.x] = FLT_MAX;
}

// ---------------- hops: h[(r*2+jj)*8+b][e] = rel[b] @ W[r][jj] + bias --
__global__ void k_hops(const float* __restrict__ rel, const float* __restrict__ W,
                       const float* __restrict__ bias, float* __restrict__ h) {
    int gt = blockIdx.x * 256 + threadIdx.x;   // 0..4095
    int e = gt & 127;
    int idx = gt >> 7;                         // (r*2+jj)*8 + b, 0..31
    int b = idx & 7;
    int rj = idx >> 3;                         // 0..3
    const float* Wp = W + rj * EDIM * EDIM;    // [k][e]
    float acc = bias[rj * EDIM + e];
    for (int k = 0; k < EDIM; ++k)
        acc += rel[b * EDIM + k] * Wp[k * EDIM + e];
    h[idx * EDIM + e] = acc;
}

// ---------------- query norms, 56 vectors ------------------------------
// order: 0..7 rel[b], 8..15 arg1[b], 16..23 arg2[b], 24..39 h1[r][b], 40..55 h2[r][b]
__global__ void k_qnorm(const float* __restrict__ rel, const float* __restrict__ a1,
                        const float* __restrict__ a2, const float* __restrict__ h,
                        float* __restrict__ qn) {
    int j = blockIdx.x;
    int l = threadIdx.x;
    const float* v;
    if (j < 8) v = rel + j * EDIM;
    else if (j < 16) v = a1 + (j - 8) * EDIM;
    else if (j < 24) v = a2 + (j - 16) * EDIM;
    else {
        int t = j - 24;                 // 0..31
        int jj = t >> 4;                // 0 = h1, 1 = h2
        int r = (t >> 3) & 1;
        int b = t & 7;
        v = h + ((r * 2 + jj) * 8 + b) * EDIM;
    }
    float p = v[l] * v[l] + v[l + 64] * v[l + 64];
    p = wave_sum(p);
    if (l == 0) qn[j] = p;
}

// ---------------- entity norms -----------------------------------------
__global__ void k_ne(const float* __restrict__ ent, float* __restrict__ ne) {
    int gt = blockIdx.x * blockDim.x + threadIdx.x;
    int wid = gt >> 6, lane = gt & 63;
    int nw = (gridDim.x * blockDim.x) >> 6;
    for (int n = wid; n < NENT; n += nw) {
        float a = ent[n * EDIM + lane];
        float b = ent[n * EDIM + lane + 64];
        float p = wave_sum(a * a + b * b);
        if (lane == 0) ne[n] = p;
    }
}

// ---------------- dots: 7 groups of 8 query rows vs facts --------------
// group g: 0 rel.fr, 1 h1r0.fr, 2 h1r1.fr, 3 h2r0.fr, 4 h2r1.fr, 5 arg1.fs, 6 arg2.fo
// dots[(g*8+j)*NFACT + f]; also writes fact norms nfr/nfs/nfo.
__global__ void k_dots(const float* __restrict__ rel, const float* __restrict__ a1,
                       const float* __restrict__ a2, const float* __restrict__ h,
                       const float* __restrict__ fr, const float* __restrict__ fs,
                       const float* __restrict__ fo, float* __restrict__ dots,
                       float* __restrict__ nfr, float* __restrict__ nfs,
                       float* __restrict__ nfo) {
    __shared__ __align__(16) float q[128 * 64];   // [e][j], j padded to 64
    for (int idx = threadIdx.x; idx < 128 * 64; idx += 256) {
        int e = idx >> 6, j = idx & 63;
        float v = 0.f;
        if (j < 56) {
            if (j < 8) v = rel[j * 128 + e];
            else if (j < 16) v = a1[(j - 8) * 128 + e];
            else if (j < 24) v = a2[(j - 16) * 128 + e];
            else {
                int t2 = j - 24;
                int jj = t2 >> 4, r = (t2 >> 3) & 1, bb = t2 & 7;
                v = h[((r * 2 + jj) * 8 + bb) * 128 + e];
            }
        }
        q[idx] = v;
    }
    __syncthreads();

    int tg = blockIdx.x * 256 + threadIdx.x;      // 0..28671
    int f = tg & (NFACT - 1);
    int g = tg >> 12;                             // 0..6
    const float* rowp = ((g < 5) ? fr : (g == 5 ? fs : fo)) + f * EDIM;
    const int qbase_tab[7] = {0, 24, 32, 40, 48, 8, 16};
    int qb = qbase_tab[g];

    float acc[8] = {0, 0, 0, 0, 0, 0, 0, 0};
    float nrm = 0.f;
    const float4* rp4 = (const float4*)rowp;
#pragma unroll 4
    for (int es = 0; es < 32; ++es) {
        float4 x = rp4[es];
        float xs[4] = {x.x, x.y, x.z, x.w};
        nrm += x.x * x.x + x.y * x.y + x.z * x.z + x.w * x.w;
#pragma unroll
        for (int c = 0; c < 4; ++c) {
            int e = es * 4 + c;
            float xe = xs[c];
            float4 q0 = *(const float4*)&q[e * 64 + qb];
            float4 q1 = *(const float4*)&q[e * 64 + qb + 4];
            acc[0] += xe * q0.x; acc[1] += xe * q0.y;
            acc[2] += xe * q0.z; acc[3] += xe * q0.w;
            acc[4] += xe * q1.x; acc[5] += xe * q1.y;
            acc[6] += xe * q1.z; acc[7] += xe * q1.w;
        }
    }
#pragma unroll
    for (int j = 0; j < 8; ++j) dots[(g * 8 + j) * NFACT + f] = acc[j];
    if (g == 0) nfr[f] = nrm;
    else if (g == 5) nfs[f] = nrm;
    else if (g == 6) nfo[f] = nrm;
}

// ---------------- combine dots -> c1, qz, base_min ---------------------
// qz[(r*8+b)][f] = clamp-dist(h2[r][b], fr[f]) + clamp-dist(arg2[b], fo[f])
__global__ void k_combine(const float* __restrict__ dots, const float* __restrict__ qn,
                          const float* __restrict__ nfr, const float* __restrict__ nfs,
                          const float* __restrict__ nfo, float* __restrict__ c1,
                          float* __restrict__ qz, float* __restrict__ base_min) {
    __shared__ unsigned sbase;
    if (threadIdx.x == 0) sbase = 0x7f7fffffu;    // FLT_MAX bits
    __syncthreads();
    int gid = blockIdx.x * 256 + threadIdx.x;     // 0..32767
    int b = gid >> 12;
    int f = gid & (NFACT - 1);
    float nfrf = nfr[f], nfsf = nfs[f], nfof = nfo[f];
    float qa1v = fmaxf(qn[8 + b] + nfsf - 2.f * dots[(5 * 8 + b) * NFACT + f], 0.f);
    float qa2v = fmaxf(qn[16 + b] + nfof - 2.f * dots[(6 * 8 + b) * NFACT + f], 0.f);
    float cb = fmaxf(qn[b] + nfrf - 2.f * dots[(0 * 8 + b) * NFACT + f], 0.f) + qa1v + qa2v;
#pragma unroll
    for (int r = 0; r < 2; ++r) {
        float t1 = fmaxf(qn[24 + r * 8 + b] + nfrf - 2.f * dots[((1 + r) * 8 + b) * NFACT + f], 0.f);
        c1[(r * 8 + b) * NFACT + f] = t1 + qa1v;
        float t2 = fmaxf(qn[40 + r * 8 + b] + nfrf - 2.f * dots[((3 + r) * 8 + b) * NFACT + f], 0.f);
        qz[(r * 8 + b) * NFACT + f] = t2 + qa2v;
    }
    atomicMin(&sbase, __float_as_uint(cb));
    __syncthreads();
    if (threadIdx.x == 0) atomicMin((unsigned*)&base_min[b], sbase);
}

// ---------------- fused ent x fo GEMM + min-plus -----------------------
// block: 64 entities x 512-fact slice, inner tiles of 32 facts.
__global__ __launch_bounds__(256) void k_minplus(
        const float* __restrict__ ent, const float* __restrict__ fo,
        const float* __restrict__ ne, const float* __restrict__ nfo,
        const float* __restrict__ c1, float* __restrict__ msum) {
    __shared__ __align__(16) float ent_l[64 * 132];
    __shared__ __align__(16) float fo_l[32 * 132];
    __shared__ float d_l[64 * 33];
    __shared__ float c_l[16 * 32];
    __shared__ float ne_l[64];
    __shared__ float nfo_l[32];
    int tid = threadIdx.x;
    int nb = blockIdx.x * 64;
    int fs0 = blockIdx.y * 512;

    for (int idx = tid; idx < 64 * 128; idx += 256) {
        int row = idx >> 7, col = idx & 127;
        ent_l[row * 132 + col] = ent[(nb + row) * EDIM + col];
    }
    if (tid < 64) ne_l[tid] = ne[nb + tid];

    int ng = tid & 15, fg = tid >> 4;     // gemm: rows ng+16i, cols fg+16j
    int en = tid & 63, brg = tid >> 6;    // epilogue: entity en, br group
    float m[4] = {FLT_MAX, FLT_MAX, FLT_MAX, FLT_MAX};

    for (int ci = 0; ci < 16; ++ci) {
        int fb = fs0 + ci * 32;
        __syncthreads();   // staging vs previous epilogue readers (and initial ent stage)
        for (int idx = tid; idx < 32 * 128; idx += 256) {
            int row = idx >> 7, col = idx & 127;
            fo_l[row * 132 + col] = fo[(fb + row) * EDIM + col];
        }
        if (tid < 32) nfo_l[tid] = nfo[fb + tid];
        for (int idx = tid; idx < 512; idx += 256) {
            int row = idx >> 5, col = idx & 31;
            c_l[idx] = c1[row * NFACT + fb + col];
        }
        __syncthreads();

        float acc[4][2];
#pragma unroll
        for (int i = 0; i < 4; ++i) { acc[i][0] = 0.f; acc[i][1] = 0.f; }
#pragma unroll 4
        for (int es = 0; es < 32; ++es) {
            float4 bv0 = *(const float4*)&fo_l[fg * 132 + es * 4];
            float4 bv1 = *(const float4*)&fo_l[(fg + 16) * 132 + es * 4];
#pragma unroll
            for (int i = 0; i < 4; ++i) {
                float4 av = *(const float4*)&ent_l[(ng + 16 * i) * 132 + es * 4];
                acc[i][0] += av.x * bv0.x + av.y * bv0.y + av.z * bv0.z + av.w * bv0.w;
                acc[i][1] += av.x * bv1.x + av.y * bv1.y + av.z * bv1.z + av.w * bv1.w;
            }
        }
#pragma unroll
        for (int i = 0; i < 4; ++i)
#pragma unroll
            for (int j = 0; j < 2; ++j)
                d_l[(ng + 16 * i) * 33 + fg + 16 * j] =
                    fmaxf(ne_l[ng + 16 * i] + nfo_l[fg + 16 * j] - 2.f * acc[i][j], 0.f);
        __syncthreads();

        for (int f = 0; f < 32; ++f) {
            float dv = d_l[en * 33 + f];
#pragma unroll
            for (int q = 0; q < 4; ++q)
                m[q] = fminf(m[q], c_l[(brg * 4 + q) * 32 + f] + dv);
        }
    }
#pragma unroll
    for (int q = 0; q < 4; ++q)
        atomicMin((unsigned*)&msum[(brg * 4 + q) * NENT + nb + en], __float_as_uint(m[q]));
}

// ---------------- top-10 smallest msum per (r,b) row -------------------
__global__ void k_topk(const float* __restrict__ msum, int* __restrict__ z_idx,
                       float* __restrict__ z_msum) {
    __shared__ float sv[NENT];
    __shared__ float rv[256];
    __shared__ int ri[256];
    int br = blockIdx.x, t = threadIdx.x;
    for (int i = t; i < NENT; i += 256) sv[i] = msum[br * NENT + i];
    __syncthreads();
    for (int it = 0; it < KTOP; ++it) {
        float best = FLT_MAX;
        int bi = 1 << 30;
        for (int i = t; i < NENT; i += 256) {
            float v = sv[i];
            if (v < best || (v == best && i < bi)) { best = v; bi = i; }
        }
        rv[t] = best; ri[t] = bi;
        __syncthreads();
        for (int s = 128; s > 0; s >>= 1) {
            if (t < s) {
                float ov = rv[t + s]; int oi = ri[t + s];
                if (ov < rv[t] || (ov == rv[t] && oi < ri[t])) { rv[t] = ov; ri[t] = oi; }
            }
            __syncthreads();
        }
        if (t == 0) {
            z_idx[br * KTOP + it] = ri[0];
            z_msum[br * KTOP + it] = rv[0];
            sv[ri[0]] = FLT_MAX;
        }
        __syncthreads();
    }
}

// ---------------- z2: tiled GEMM-style min-plus over facts -------------
// rows = 160 (br*10+k), cols = 4096 facts, K = 128.
// block: 32 rows x 256 facts (inner tiles of 32), grid (5, 16).
__global__ __launch_bounds__(256) void k_z2(
        const float* __restrict__ ent, const float* __restrict__ fs,
        const float* __restrict__ nfs, const float* __restrict__ ne,
        const float* __restrict__ qz, const int* __restrict__ z_idx,
        float* __restrict__ z2sum) {
    __shared__ __align__(16) float z_l[32 * 132];
    __shared__ __align__(16) float fs_l[32 * 132];
    __shared__ float qz_l[32 * 33];
    __shared__ float nz_l[32];
    __shared__ float nfs_l[32];
    __shared__ float mred[32 * 17];
    int tid = threadIdx.x;
    int r0 = blockIdx.x * 32;              // 0,32,...,128
    int f0 = blockIdx.y * 256;

    for (int idx = tid; idx < 32 * 128; idx += 256) {
        int row = idx >> 7, col = idx & 127;
        z_l[row * 132 + col] = ent[z_idx[r0 + row] * EDIM + col];
    }
    if (tid < 32) nz_l[tid] = ne[z_idx[r0 + tid]];

    int ng = tid & 15, fg = tid >> 4;
    float m[2] = {FLT_MAX, FLT_MAX};

    for (int ci = 0; ci < 8; ++ci) {
        int fb = f0 + ci * 32;
        __syncthreads();
        for (int idx = tid; idx < 32 * 128; idx += 256) {
            int row = idx >> 7, col = idx & 127;
            fs_l[row * 132 + col] = fs[(fb + row) * EDIM + col];
        }
        if (tid < 32) nfs_l[tid] = nfs[fb + tid];
        for (int idx = tid; idx < 32 * 32; idx += 256) {
            int row = idx >> 5, col = idx & 31;
            int br = (r0 + row) / KTOP;
            qz_l[row * 33 + col] = qz[br * NFACT + fb + col];
        }
        __syncthreads();

        float acc[2][2] = {{0.f, 0.f}, {0.f, 0.f}};
#pragma unroll 4
        for (int es = 0; es < 32; ++es) {
            float4 bv0 = *(const float4*)&fs_l[fg * 132 + es * 4];
            float4 bv1 = *(const float4*)&fs_l[(fg + 16) * 132 + es * 4];
            float4 a0 = *(const float4*)&z_l[ng * 132 + es * 4];
            float4 a1 = *(const float4*)&z_l[(ng + 16) * 132 + es * 4];
            acc[0][0] += a0.x * bv0.x + a0.y * bv0.y + a0.z * bv0.z + a0.w * bv0.w;
            acc[0][1] += a0.x * bv1.x + a0.y * bv1.y + a0.z * bv1.z + a0.w * bv1.w;
            acc[1][0] += a1.x * bv0.x + a1.y * bv0.y + a1.z * bv0.z + a1.w * bv0.w;
            acc[1][1] += a1.x * bv1.x + a1.y * bv1.y + a1.z * bv1.z + a1.w * bv1.w;
        }
#pragma unroll
        for (int i = 0; i < 2; ++i)
#pragma unroll
            for (int j = 0; j < 2; ++j) {
                int row = ng + 16 * i, f = fg + 16 * j;
                float val = qz_l[row * 33 + f] +
                            fmaxf(nz_l[row] + nfs_l[f] - 2.f * acc[i][j], 0.f);
                m[i] = fminf(m[i], val);
            }
    }
    mred[ng * 17 + fg] = m[0];
    mred[(ng + 16) * 17 + fg] = m[1];
    __syncthreads();
    if (tid < 32) {
        float mm = FLT_MAX;
#pragma unroll
        for (int j = 0; j < 16; ++j) mm = fminf(mm, mred[tid * 17 + j]);
        atomicMin((unsigned*)&z2sum[r0 + tid], __float_as_uint(mm));
    }
}

// ---------------- final combine ----------------------------------------
__global__ void k_final(const float* __restrict__ base_min, const float* __restrict__ z_msum,
                        const float* __restrict__ z2sum, float* __restrict__ out) {
    int b = threadIdx.x;
    if (b >= BQ) return;
    float best = expf(-0.5f * base_min[b]);
#pragma unroll
    for (int r = 0; r < 2; ++r) {
        int br = r * 8 + b;
        float rb = 0.f;
        for (int k = 0; k < KTOP; ++k) {
            float s = expf(-0.5f * fmaxf(z2sum[br * KTOP + k], z_msum[br * KTOP + k]));
            rb = fmaxf(rb, s);
        }
        best = fmaxf(best, rb);
    }
    out[b] = best;
}

extern "C" void kernel_launch(void* const* d_in, const int* in_sizes, int n_in,
                              void* d_out, int out_size, void* d_ws, size_t ws_size,
                              hipStream_t stream) {
    const float* rel = (const float*)d_in[0];
    const float* arg1 = (const float*)d_in[1];
    const float* arg2 = (const float*)d_in[2];
    const float* fr = (const float*)d_in[3];
    const float* fs = (const float*)d_in[4];
    const float* fo = (const float*)d_in[5];
    const float* ent = (const float*)d_in[6];
    const float* W = (const float*)d_in[7];
    const float* bias = (const float*)d_in[8];
    float* out = (float*)d_out;

    float* w = (float*)d_ws;
    float* h = w;                          // 4096
    float* qn = h + 4096;                  // 64
    float* nfr = qn + 64;                  // 4096
    float* nfs = nfr + 4096;               // 4096
    float* nfo = nfs + 4096;               // 4096
    float* ne = nfo + 4096;                // 2048
    float* dots = ne + 2048;               // 7*8*4096 = 229376
    float* c1 = dots + 229376;             // 16*4096 = 65536
    float* qz = c1 + 65536;                // 16*4096 = 65536
    float* msum = qz + 65536;              // 16*2048 = 32768
    float* base_min = msum + 32768;        // 8
    float* z_msum = base_min + 8;          // 160
    float* z2sum = z_msum + 160;           // 160
    int* z_idx = (int*)(z2sum + 160);      // 160

    k_init<<<64, 256, 0, stream>>>(msum, base_min, z2sum);
    k_hops<<<16, 256, 0, stream>>>(rel, W, bias, h);
    k_qnorm<<<56, 64, 0, stream>>>(rel, arg1, arg2, h, qn);
    k_ne<<<8, 256, 0, stream>>>(ent, ne);
    k_dots<<<112, 256, 0, stream>>>(rel, arg1, arg2, h, fr, fs, fo, dots, nfr, nfs, nfo);
    k_combine<<<128, 256, 0, stream>>>(dots, qn, nfr, nfs, nfo, c1, qz, base_min);
    k_minplus<<<dim3(32, 8), 256, 0, stream>>>(ent, fo, ne, nfo, c1, msum);
    k_topk<<<16, 256, 0, stream>>>(msum, z_idx, z_msum);
    k_z2<<<dim3(5, 16), 256, 0, stream>>>(ent, fs, nfs, ne, qz, z_idx, z2sum);
    k_final<<<1, 64, 0, stream>>>(base_min, z_msum, z2sum, out);
}

// Round 3
// 122.260 us; speedup vs baseline: 5.1454x; 1.9011x over previous
//
#include <hip/hip_runtime.h>
#include <hip/hip_bf16.h>
#include <float.h>

#define EDIM 128
#define NFACT 4096
#define NENT 2048
#define BQ 8
#define KTOP 10

__device__ __forceinline__ float wave_sum(float v) {
#pragma unroll
    for (int m = 32; m; m >>= 1) v += __shfl_xor(v, m, 64);
    return v;
}

// ---------------- prep: h+qnorm(h), qnorm(rel/a1/a2), ne, inits --------
// grid 151 x 256
__global__ void k_prep(const float* __restrict__ rel, const float* __restrict__ a1,
                       const float* __restrict__ a2, const float* __restrict__ W,
                       const float* __restrict__ bias, const float* __restrict__ ent,
                       float* __restrict__ h, float* __restrict__ qn,
                       float* __restrict__ ne, float* __restrict__ msum,
                       float* __restrict__ base_min, float* __restrict__ z2sum) {
    int blk = blockIdx.x;
    int tid = threadIdx.x;
    if (blk < 16) {
        // h rows 2*blk, 2*blk+1 (128 threads per row) + their norms
        __shared__ float s_[4];
        int row = blk * 2 + (tid >> 7);        // 0..31 = (r*2+jj)*8+b
        int e = tid & 127;
        int b = row & 7, rj = row >> 3;
        const float* Wp = W + rj * EDIM * EDIM;
        float acc = bias[rj * EDIM + e];
        for (int k = 0; k < EDIM; ++k)
            acc += rel[b * EDIM + k] * Wp[k * EDIM + e];
        h[row * EDIM + e] = acc;
        float p = wave_sum(acc * acc);
        if ((tid & 63) == 0) s_[tid >> 6] = p;
        __syncthreads();
        if ((tid & 127) == 0) {
            int half = tid >> 7;
            float nn = s_[half * 2] + s_[half * 2 + 1];
            int jj = (row >> 3) & 1, r = row >> 4, bb = row & 7;
            qn[24 + jj * 16 + r * 8 + bb] = nn;
        }
    } else if (blk < 22) {
        // norms of rel/arg1/arg2 (24 rows), wave per row
        int j = (blk - 16) * 4 + (tid >> 6);
        int l = tid & 63;
        if (j < 24) {
            const float* v = (j < 8) ? rel + j * EDIM
                           : (j < 16) ? a1 + (j - 8) * EDIM : a2 + (j - 16) * EDIM;
            float p = wave_sum(v[l] * v[l] + v[l + 64] * v[l + 64]);
            if (l == 0) qn[j] = p;
        }
    } else if (blk < 86) {
        // entity norms: 64 blocks x 32 rows
        int base = (blk - 22) * 32;
        int lane = tid & 63, wv = tid >> 6;
        for (int rr = wv; rr < 32; rr += 4) {
            int n = base + rr;
            float a = ent[n * EDIM + lane], b2 = ent[n * EDIM + lane + 64];
            float p = wave_sum(a * a + b2 * b2);
            if (lane == 0) ne[n] = p;
        }
    } else if (blk < 150) {
        // msum init: 64 blocks x 512
        int i = (blk - 86) * 512 + tid;
        msum[i] = FLT_MAX;
        msum[i + 256] = FLT_MAX;
    } else {
        if (tid < BQ) base_min[tid] = FLT_MAX;
        if (tid < 160) z2sum[tid] = FLT_MAX;
    }
}

// ---------------- dots: 7 groups of 8 query rows vs facts --------------
__global__ void k_dots(const float* __restrict__ rel, const float* __restrict__ a1,
                       const float* __restrict__ a2, const float* __restrict__ h,
                       const float* __restrict__ fr, const float* __restrict__ fs,
                       const float* __restrict__ fo, float* __restrict__ dots,
                       float* __restrict__ nfr, float* __restrict__ nfs,
                       float* __restrict__ nfo) {
    __shared__ __align__(16) float q[128 * 64];   // [e][j], j padded to 64
    for (int idx = threadIdx.x; idx < 128 * 64; idx += 256) {
        int e = idx >> 6, j = idx & 63;
        float v = 0.f;
        if (j < 56) {
            if (j < 8) v = rel[j * 128 + e];
            else if (j < 16) v = a1[(j - 8) * 128 + e];
            else if (j < 24) v = a2[(j - 16) * 128 + e];
            else {
                int t2 = j - 24;
                int jj = t2 >> 4, r = (t2 >> 3) & 1, bb = t2 & 7;
                v = h[((r * 2 + jj) * 8 + bb) * 128 + e];
            }
        }
        q[idx] = v;
    }
    __syncthreads();

    int tg = blockIdx.x * 256 + threadIdx.x;      // 0..28671
    int f = tg & (NFACT - 1);
    int g = tg >> 12;                             // 0..6
    const float* rowp = ((g < 5) ? fr : (g == 5 ? fs : fo)) + f * EDIM;
    const int qbase_tab[7] = {0, 24, 32, 40, 48, 8, 16};
    int qb = qbase_tab[g];

    float acc[8] = {0, 0, 0, 0, 0, 0, 0, 0};
    float nrm = 0.f;
    const float4* rp4 = (const float4*)rowp;
#pragma unroll 4
    for (int es = 0; es < 32; ++es) {
        float4 x = rp4[es];
        float xs[4] = {x.x, x.y, x.z, x.w};
        nrm += x.x * x.x + x.y * x.y + x.z * x.z + x.w * x.w;
#pragma unroll
        for (int c = 0; c < 4; ++c) {
            int e = es * 4 + c;
            float xe = xs[c];
            float4 q0 = *(const float4*)&q[e * 64 + qb];
            float4 q1 = *(const float4*)&q[e * 64 + qb + 4];
            acc[0] += xe * q0.x; acc[1] += xe * q0.y;
            acc[2] += xe * q0.z; acc[3] += xe * q0.w;
            acc[4] += xe * q1.x; acc[5] += xe * q1.y;
            acc[6] += xe * q1.z; acc[7] += xe * q1.w;
        }
    }
#pragma unroll
    for (int j = 0; j < 8; ++j) dots[(g * 8 + j) * NFACT + f] = acc[j];
    if (g == 0) nfr[f] = nrm;
    else if (g == 5) nfs[f] = nrm;
    else if (g == 6) nfo[f] = nrm;
}

// ---------------- combine dots -> c1, qz, base_min ---------------------
__global__ void k_combine(const float* __restrict__ dots, const float* __restrict__ qn,
                          const float* __restrict__ nfr, const float* __restrict__ nfs,
                          const float* __restrict__ nfo, float* __restrict__ c1,
                          float* __restrict__ qz, float* __restrict__ base_min) {
    __shared__ unsigned sbase;
    if (threadIdx.x == 0) sbase = 0x7f7fffffu;
    __syncthreads();
    int gid = blockIdx.x * 256 + threadIdx.x;     // 0..32767
    int b = gid >> 12;
    int f = gid & (NFACT - 1);
    float nfrf = nfr[f], nfsf = nfs[f], nfof = nfo[f];
    float qa1v = fmaxf(qn[8 + b] + nfsf - 2.f * dots[(5 * 8 + b) * NFACT + f], 0.f);
    float qa2v = fmaxf(qn[16 + b] + nfof - 2.f * dots[(6 * 8 + b) * NFACT + f], 0.f);
    float cb = fmaxf(qn[b] + nfrf - 2.f * dots[(0 * 8 + b) * NFACT + f], 0.f) + qa1v + qa2v;
#pragma unroll
    for (int r = 0; r < 2; ++r) {
        float t1 = fmaxf(qn[24 + r * 8 + b] + nfrf - 2.f * dots[((1 + r) * 8 + b) * NFACT + f], 0.f);
        c1[(r * 8 + b) * NFACT + f] = t1 + qa1v;
        float t2 = fmaxf(qn[40 + r * 8 + b] + nfrf - 2.f * dots[((3 + r) * 8 + b) * NFACT + f], 0.f);
        qz[(r * 8 + b) * NFACT + f] = t2 + qa2v;
    }
    atomicMin(&sbase, __float_as_uint(cb));
    __syncthreads();
    if (threadIdx.x == 0) atomicMin((unsigned*)&base_min[b], sbase);
}

// ---------------- fused ent x fo GEMM + min-plus (4x4 reg tiles) -------
// grid (32, 16): 64 entities x 256 facts per block, inner tiles of 64.
__global__ __launch_bounds__(256) void k_minplus(
        const float* __restrict__ ent, const float* __restrict__ fo,
        const float* __restrict__ ne, const float* __restrict__ nfo,
        const float* __restrict__ c1, float* __restrict__ msum) {
    __shared__ __align__(16) float ent_l[64 * 132];   // 33792 B
    __shared__ __align__(16) float fo_l[64 * 132];    // 33792 B (reused as red)
    __shared__ __align__(16) float c_t[64 * 20];      // transposed c: [f][br]
    __shared__ float ne_l[64];
    __shared__ float nfo_l[64];
    int tid = threadIdx.x;
    int nb = blockIdx.x * 64;
    int f0 = blockIdx.y * 256;
    int ng = tid & 15, fg = tid >> 4;

    {
        const float4* src = (const float4*)(ent + nb * EDIM);
        for (int idx = tid; idx < 64 * 32; idx += 256) {
            int row = idx >> 5, c4 = idx & 31;
            *(float4*)&ent_l[row * 132 + c4 * 4] = src[row * 32 + c4];
        }
        if (tid < 64) ne_l[tid] = ne[nb + tid];
    }

    float minv[16][4];
#pragma unroll
    for (int br = 0; br < 16; ++br)
#pragma unroll
        for (int i = 0; i < 4; ++i) minv[br][i] = FLT_MAX;

    for (int ci = 0; ci < 4; ++ci) {
        int fb = f0 + ci * 64;
        __syncthreads();
        {
            const float4* src = (const float4*)(fo + fb * EDIM);
            for (int idx = tid; idx < 64 * 32; idx += 256) {
                int row = idx >> 5, c4 = idx & 31;
                *(float4*)&fo_l[row * 132 + c4 * 4] = src[row * 32 + c4];
            }
            if (tid < 64) nfo_l[tid] = nfo[fb + tid];
            for (int idx = tid; idx < 1024; idx += 256) {
                int f = idx & 63, br = idx >> 6;
                c_t[f * 20 + br] = c1[br * NFACT + fb + f];
            }
        }
        __syncthreads();

        float acc[4][4];
#pragma unroll
        for (int i = 0; i < 4; ++i)
#pragma unroll
            for (int j = 0; j < 4; ++j) acc[i][j] = 0.f;

#pragma unroll 2
        for (int es = 0; es < 32; ++es) {
            float4 b0 = *(const float4*)&fo_l[fg * 132 + es * 4];
            float4 b1 = *(const float4*)&fo_l[(fg + 16) * 132 + es * 4];
            float4 b2 = *(const float4*)&fo_l[(fg + 32) * 132 + es * 4];
            float4 b3 = *(const float4*)&fo_l[(fg + 48) * 132 + es * 4];
#pragma unroll
            for (int i = 0; i < 4; ++i) {
                float4 a = *(const float4*)&ent_l[(ng + 16 * i) * 132 + es * 4];
                acc[i][0] += a.x * b0.x + a.y * b0.y + a.z * b0.z + a.w * b0.w;
                acc[i][1] += a.x * b1.x + a.y * b1.y + a.z * b1.z + a.w * b1.w;
                acc[i][2] += a.x * b2.x + a.y * b2.y + a.z * b2.z + a.w * b2.w;
                acc[i][3] += a.x * b3.x + a.y * b3.y + a.z * b3.z + a.w * b3.w;
            }
        }
        float d[4][4];
#pragma unroll
        for (int i = 0; i < 4; ++i) {
            float nei = ne_l[ng + 16 * i];
#pragma unroll
            for (int j = 0; j < 4; ++j)
                d[i][j] = fmaxf(nei + nfo_l[fg + 16 * j] - 2.f * acc[i][j], 0.f);
        }
#pragma unroll
        for (int j = 0; j < 4; ++j) {
            int f = fg + 16 * j;
#pragma unroll
            for (int brq = 0; brq < 4; ++brq) {
                float4 c4 = *(const float4*)&c_t[f * 20 + brq * 4];
#pragma unroll
                for (int i = 0; i < 4; ++i) {
                    minv[brq * 4 + 0][i] = fminf(minv[brq * 4 + 0][i], c4.x + d[i][j]);
                    minv[brq * 4 + 1][i] = fminf(minv[brq * 4 + 1][i], c4.y + d[i][j]);
                    minv[brq * 4 + 2][i] = fminf(minv[brq * 4 + 2][i], c4.z + d[i][j]);
                    minv[brq * 4 + 3][i] = fminf(minv[brq * 4 + 3][i], c4.w + d[i][j]);
                }
            }
        }
    }
    // reduce across fg: shuffle (xor 16, 32) collapses the 4 fg's per wave
#pragma unroll
    for (int br = 0; br < 16; ++br)
#pragma unroll
        for (int i = 0; i < 4; ++i) {
            float v = minv[br][i];
            v = fminf(v, __shfl_xor(v, 16, 64));
            v = fminf(v, __shfl_xor(v, 32, 64));
            minv[br][i] = v;
        }
    __syncthreads();
    float* red = fo_l;   // reuse: [4 waves][16 ng][65]
    if ((tid & 63) < 16) {
        int w = tid >> 6;
#pragma unroll
        for (int br = 0; br < 16; ++br)
#pragma unroll
            for (int i = 0; i < 4; ++i)
                red[(w * 16 + ng) * 65 + br * 4 + i] = minv[br][i];
    }
    __syncthreads();
    for (int p = tid; p < 1024; p += 256) {
        int br = p >> 6, en = p & 63;
        int ngo = en & 15, io = en >> 4;
        float v = red[ngo * 65 + br * 4 + io];
        v = fminf(v, red[(16 + ngo) * 65 + br * 4 + io]);
        v = fminf(v, red[(32 + ngo) * 65 + br * 4 + io]);
        v = fminf(v, red[(48 + ngo) * 65 + br * 4 + io]);
        atomicMin((unsigned*)&msum[br * NENT + nb + en], __float_as_uint(v));
    }
}

// ---------------- top-10 smallest msum per (r,b) row (shuffle) ---------
__global__ void k_topk(const float* __restrict__ msum, int* __restrict__ z_idx,
                       float* __restrict__ z_msum) {
    __shared__ float sv[4];
    __shared__ int si[4];
    __shared__ float wv_;
    __shared__ int wi_;
    int br = blockIdx.x, t = threadIdx.x;
    float v[8];
#pragma unroll
    for (int p = 0; p < 8; ++p) v[p] = msum[br * NENT + t + 256 * p];
    for (int it = 0; it < KTOP; ++it) {
        float best = FLT_MAX;
        int bi = 1 << 30;
#pragma unroll
        for (int p = 0; p < 8; ++p) {
            int idx = t + 256 * p;
            if (v[p] < best) { best = v[p]; bi = idx; }
        }
#pragma unroll
        for (int m = 32; m; m >>= 1) {
            float ov = __shfl_xor(best, m, 64);
            int oi = __shfl_xor(bi, m, 64);
            if (ov < best || (ov == best && oi < bi)) { best = ov; bi = oi; }
        }
        int lane = t & 63, w = t >> 6;
        if (lane == 0) { sv[w] = best; si[w] = bi; }
        __syncthreads();
        if (t == 0) {
            float bb = sv[0]; int bj = si[0];
            for (int ww = 1; ww < 4; ++ww)
                if (sv[ww] < bb || (sv[ww] == bb && si[ww] < bj)) { bb = sv[ww]; bj = si[ww]; }
            z_idx[br * KTOP + it] = bj;
            z_msum[br * KTOP + it] = bb;
            wv_ = bb; wi_ = bj;
        }
        __syncthreads();
        int wi = wi_;
        if ((wi & 255) == t) {
            int p_ = wi >> 8;
#pragma unroll
            for (int p = 0; p < 8; ++p)
                if (p == p_) v[p] = FLT_MAX;
        }
        __syncthreads();
    }
}

// ---------------- z2: tiled GEMM-style min-plus over facts -------------
// grid (5, 32): 32 rows x 128 facts per block, inner tiles of 32.
__global__ __launch_bounds__(256) void k_z2(
        const float* __restrict__ ent, const float* __restrict__ fs,
        const float* __restrict__ nfs, const float* __restrict__ ne,
        const float* __restrict__ qz, const int* __restrict__ z_idx,
        float* __restrict__ z2sum) {
    __shared__ __align__(16) float z_l[32 * 132];
    __shared__ __align__(16) float fs_l[32 * 132];
    __shared__ float qz_l[32 * 33];
    __shared__ float nz_l[32];
    __shared__ float nfs_l[32];
    __shared__ float mred[32 * 17];
    int tid = threadIdx.x;
    int r0 = blockIdx.x * 32;
    int f0 = blockIdx.y * 128;

    for (int idx = tid; idx < 32 * 128; idx += 256) {
        int row = idx >> 7, col = idx & 127;
        z_l[row * 132 + col] = ent[z_idx[r0 + row] * EDIM + col];
    }
    if (tid < 32) nz_l[tid] = ne[z_idx[r0 + tid]];

    int ng = tid & 15, fg = tid >> 4;
    float m[2] = {FLT_MAX, FLT_MAX};

    for (int ci = 0; ci < 4; ++ci) {
        int fb = f0 + ci * 32;
        __syncthreads();
        for (int idx = tid; idx < 32 * 128; idx += 256) {
            int row = idx >> 7, col = idx & 127;
            fs_l[row * 132 + col] = fs[(fb + row) * EDIM + col];
        }
        if (tid < 32) nfs_l[tid] = nfs[fb + tid];
        for (int idx = tid; idx < 32 * 32; idx += 256) {
            int row = idx >> 5, col = idx & 31;
            int br = (r0 + row) / KTOP;
            qz_l[row * 33 + col] = qz[br * NFACT + fb + col];
        }
        __syncthreads();

        float acc[2][2] = {{0.f, 0.f}, {0.f, 0.f}};
#pragma unroll 4
        for (int es = 0; es < 32; ++es) {
            float4 bv0 = *(const float4*)&fs_l[fg * 132 + es * 4];
            float4 bv1 = *(const float4*)&fs_l[(fg + 16) * 132 + es * 4];
            float4 a0 = *(const float4*)&z_l[ng * 132 + es * 4];
            float4 a1 = *(const float4*)&z_l[(ng + 16) * 132 + es * 4];
            acc[0][0] += a0.x * bv0.x + a0.y * bv0.y + a0.z * bv0.z + a0.w * bv0.w;
            acc[0][1] += a0.x * bv1.x + a0.y * bv1.y + a0.z * bv1.z + a0.w * bv1.w;
            acc[1][0] += a1.x * bv0.x + a1.y * bv0.y + a1.z * bv0.z + a1.w * bv0.w;
            acc[1][1] += a1.x * bv1.x + a1.y * bv1.y + a1.z * bv1.z + a1.w * bv1.w;
        }
#pragma unroll
        for (int i = 0; i < 2; ++i)
#pragma unroll
            for (int j = 0; j < 2; ++j) {
                int row = ng + 16 * i, f = fg + 16 * j;
                float val = qz_l[row * 33 + f] +
                            fmaxf(nz_l[row] + nfs_l[f] - 2.f * acc[i][j], 0.f);
                m[i] = fminf(m[i], val);
            }
    }
    mred[ng * 17 + fg] = m[0];
    mred[(ng + 16) * 17 + fg] = m[1];
    __syncthreads();
    if (tid < 32) {
        float mm = FLT_MAX;
#pragma unroll
        for (int j = 0; j < 16; ++j) mm = fminf(mm, mred[tid * 17 + j]);
        atomicMin((unsigned*)&z2sum[r0 + tid], __float_as_uint(mm));
    }
}

// ---------------- final combine ----------------------------------------
__global__ void k_final(const float* __restrict__ base_min, const float* __restrict__ z_msum,
                        const float* __restrict__ z2sum, float* __restrict__ out) {
    int b = threadIdx.x;
    if (b >= BQ) return;
    float best = expf(-0.5f * base_min[b]);
#pragma unroll
    for (int r = 0; r < 2; ++r) {
        int br = r * 8 + b;
        float rb = 0.f;
        for (int k = 0; k < KTOP; ++k) {
            float s = expf(-0.5f * fmaxf(z2sum[br * KTOP + k], z_msum[br * KTOP + k]));
            rb = fmaxf(rb, s);
        }
        best = fmaxf(best, rb);
    }
    out[b] = best;
}

extern "C" void kernel_launch(void* const* d_in, const int* in_sizes, int n_in,
                              void* d_out, int out_size, void* d_ws, size_t ws_size,
                              hipStream_t stream) {
    const float* rel = (const float*)d_in[0];
    const float* arg1 = (const float*)d_in[1];
    const float* arg2 = (const float*)d_in[2];
    const float* fr = (const float*)d_in[3];
    const float* fs = (const float*)d_in[4];
    const float* fo = (const float*)d_in[5];
    const float* ent = (const float*)d_in[6];
    const float* W = (const float*)d_in[7];
    const float* bias = (const float*)d_in[8];
    float* out = (float*)d_out;

    float* w = (float*)d_ws;
    float* h = w;                          // 4096
    float* qn = h + 4096;                  // 64
    float* nfr = qn + 64;                  // 4096
    float* nfs = nfr + 4096;               // 4096
    float* nfo = nfs + 4096;               // 4096
    float* ne = nfo + 4096;                // 2048
    float* dots = ne + 2048;               // 229376
    float* c1 = dots + 229376;             // 65536
    float* qz = c1 + 65536;                // 65536
    float* msum = qz + 65536;              // 32768
    float* base_min = msum + 32768;        // 8
    float* z_msum = base_min + 8;          // 160
    float* z2sum = z_msum + 160;           // 160
    int* z_idx = (int*)(z2sum + 160);      // 160

    k_prep<<<151, 256, 0, stream>>>(rel, arg1, arg2, W, bias, ent,
                                    h, qn, ne, msum, base_min, z2sum);
    k_dots<<<112, 256, 0, stream>>>(rel, arg1, arg2, h, fr, fs, fo, dots, nfr, nfs, nfo);
    k_combine<<<128, 256, 0, stream>>>(dots, qn, nfr, nfs, nfo, c1, qz, base_min);
    k_minplus<<<dim3(32, 16), 256, 0, stream>>>(ent, fo, ne, nfo, c1, msum);
    k_topk<<<16, 256, 0, stream>>>(msum, z_idx, z_msum);
    k_z2<<<dim3(5, 32), 256, 0, stream>>>(ent, fs, nfs, ne, qz, z_idx, z2sum);
    k_final<<<1, 64, 0, stream>>>(base_min, z_msum, z2sum, out);
}

// Round 4
// 95.732 us; speedup vs baseline: 6.5712x; 1.2771x over previous
//
#include <hip/hip_runtime.h>
#include <hip/hip_bf16.h>
#include <float.h>

#define EDIM 128
#define NFACT 4096
#define NENT 2048
#define BQ 8
#define KTOP 10

typedef float f32x4 __attribute__((ext_vector_type(4)));
typedef __bf16 bf16x8 __attribute__((ext_vector_type(8)));

__device__ __forceinline__ float wave_sum(float v) {
#pragma unroll
    for (int m = 32; m; m >>= 1) v += __shfl_xor(v, m, 64);
    return v;
}

__device__ __forceinline__ unsigned short bfbits(float x) {
    __bf16 h = (__bf16)x;
    return __builtin_bit_cast(unsigned short, h);
}

// ---------------- prep: h+qnorm(h), qnorms, ne, inits, bf16-split conv -
// grid 919 x 256
__global__ void k_prep(const float* __restrict__ rel, const float* __restrict__ a1,
                       const float* __restrict__ a2, const float* __restrict__ W,
                       const float* __restrict__ bias, const float* __restrict__ ent,
                       const float* __restrict__ fo,
                       float* __restrict__ h, float* __restrict__ qn,
                       float* __restrict__ ne, float* __restrict__ msum,
                       float* __restrict__ base_min, float* __restrict__ z2sum,
                       unsigned short* __restrict__ entb, unsigned short* __restrict__ fob) {
    int blk = blockIdx.x;
    int tid = threadIdx.x;
    if (blk < 16) {
        __shared__ float s_[4];
        int row = blk * 2 + (tid >> 7);        // 0..31 = (r*2+jj)*8+b
        int e = tid & 127;
        int b = row & 7, rj = row >> 3;
        const float* Wp = W + rj * EDIM * EDIM;
        float acc = bias[rj * EDIM + e];
        for (int k = 0; k < EDIM; ++k)
            acc += rel[b * EDIM + k] * Wp[k * EDIM + e];
        h[row * EDIM + e] = acc;
        float p = wave_sum(acc * acc);
        if ((tid & 63) == 0) s_[tid >> 6] = p;
        __syncthreads();
        if ((tid & 127) == 0) {
            int half = tid >> 7;
            float nn = s_[half * 2] + s_[half * 2 + 1];
            int rr = row + half * 0;
            int jj = (rr >> 3) & 1, r = rr >> 4, bb = rr & 7;
            qn[24 + jj * 16 + r * 8 + bb] = nn;
        }
    } else if (blk < 22) {
        int j = (blk - 16) * 4 + (tid >> 6);
        int l = tid & 63;
        if (j < 24) {
            const float* v = (j < 8) ? rel + j * EDIM
                           : (j < 16) ? a1 + (j - 8) * EDIM : a2 + (j - 16) * EDIM;
            float p = wave_sum(v[l] * v[l] + v[l + 64] * v[l + 64]);
            if (l == 0) qn[j] = p;
        }
    } else if (blk < 86) {
        int base = (blk - 22) * 32;
        int lane = tid & 63, wv = tid >> 6;
        for (int rr = wv; rr < 32; rr += 4) {
            int n = base + rr;
            float a = ent[n * EDIM + lane], b2 = ent[n * EDIM + lane + 64];
            float p = wave_sum(a * a + b2 * b2);
            if (lane == 0) ne[n] = p;
        }
    } else if (blk < 150) {
        int i = (blk - 86) * 512 + tid;
        msum[i] = FLT_MAX;
        msum[i + 256] = FLT_MAX;
    } else if (blk == 150) {
        if (tid < BQ) base_min[tid] = FLT_MAX;
        if (tid < 160) z2sum[tid] = FLT_MAX;
    } else {
        // split-bf16 conversion: 6144 rows (2048 ent + 4096 fo) x 128
        int idx = (blk - 151) * 1024 + tid * 4;
        int row = idx >> 7, col = idx & 127;
        const float* src = (row < NENT) ? (ent + row * EDIM + col)
                                        : (fo + (row - NENT) * EDIM + col);
        unsigned short* dst = (row < NENT) ? (entb + row * 256)
                                           : (fob + (row - NENT) * 256);
        float4 x = *(const float4*)src;
        ushort4 hv, lv;
        hv.x = bfbits(x.x); hv.y = bfbits(x.y); hv.z = bfbits(x.z); hv.w = bfbits(x.w);
        lv.x = bfbits(x.x - (float)(__bf16)x.x);
        lv.y = bfbits(x.y - (float)(__bf16)x.y);
        lv.z = bfbits(x.z - (float)(__bf16)x.z);
        lv.w = bfbits(x.w - (float)(__bf16)x.w);
        *(ushort4*)(dst + col) = hv;
        *(ushort4*)(dst + 128 + col) = lv;
    }
}

// ---------------- dots: 7 groups of 8 query rows vs facts --------------
__global__ void k_dots(const float* __restrict__ rel, const float* __restrict__ a1,
                       const float* __restrict__ a2, const float* __restrict__ h,
                       const float* __restrict__ fr, const float* __restrict__ fs,
                       const float* __restrict__ fo, float* __restrict__ dots,
                       float* __restrict__ nfr, float* __restrict__ nfs,
                       float* __restrict__ nfo) {
    __shared__ __align__(16) float q[128 * 64];   // [e][j], j padded to 64
    for (int idx = threadIdx.x; idx < 128 * 64; idx += 256) {
        int e = idx >> 6, j = idx & 63;
        float v = 0.f;
        if (j < 56) {
            if (j < 8) v = rel[j * 128 + e];
            else if (j < 16) v = a1[(j - 8) * 128 + e];
            else if (j < 24) v = a2[(j - 16) * 128 + e];
            else {
                int t2 = j - 24;
                int jj = t2 >> 4, r = (t2 >> 3) & 1, bb = t2 & 7;
                v = h[((r * 2 + jj) * 8 + bb) * 128 + e];
            }
        }
        q[idx] = v;
    }
    __syncthreads();

    int tg = blockIdx.x * 256 + threadIdx.x;      // 0..28671
    int f = tg & (NFACT - 1);
    int g = tg >> 12;                             // 0..6
    const float* rowp = ((g < 5) ? fr : (g == 5 ? fs : fo)) + f * EDIM;
    const int qbase_tab[7] = {0, 24, 32, 40, 48, 8, 16};
    int qb = qbase_tab[g];

    float acc[8] = {0, 0, 0, 0, 0, 0, 0, 0};
    float nrm = 0.f;
    const float4* rp4 = (const float4*)rowp;
#pragma unroll 4
    for (int es = 0; es < 32; ++es) {
        float4 x = rp4[es];
        float xs[4] = {x.x, x.y, x.z, x.w};
        nrm += x.x * x.x + x.y * x.y + x.z * x.z + x.w * x.w;
#pragma unroll
        for (int c = 0; c < 4; ++c) {
            int e = es * 4 + c;
            float xe = xs[c];
            float4 q0 = *(const float4*)&q[e * 64 + qb];
            float4 q1 = *(const float4*)&q[e * 64 + qb + 4];
            acc[0] += xe * q0.x; acc[1] += xe * q0.y;
            acc[2] += xe * q0.z; acc[3] += xe * q0.w;
            acc[4] += xe * q1.x; acc[5] += xe * q1.y;
            acc[6] += xe * q1.z; acc[7] += xe * q1.w;
        }
    }
#pragma unroll
    for (int j = 0; j < 8; ++j) dots[(g * 8 + j) * NFACT + f] = acc[j];
    if (g == 0) nfr[f] = nrm;
    else if (g == 5) nfs[f] = nrm;
    else if (g == 6) nfo[f] = nrm;
}

// ---------------- combine dots -> c1, qz, base_min ---------------------
__global__ void k_combine(const float* __restrict__ dots, const float* __restrict__ qn,
                          const float* __restrict__ nfr, const float* __restrict__ nfs,
                          const float* __restrict__ nfo, float* __restrict__ c1,
                          float* __restrict__ qz, float* __restrict__ base_min) {
    __shared__ unsigned sbase;
    if (threadIdx.x == 0) sbase = 0x7f7fffffu;
    __syncthreads();
    int gid = blockIdx.x * 256 + threadIdx.x;     // 0..32767
    int b = gid >> 12;
    int f = gid & (NFACT - 1);
    float nfrf = nfr[f], nfsf = nfs[f], nfof = nfo[f];
    float qa1v = fmaxf(qn[8 + b] + nfsf - 2.f * dots[(5 * 8 + b) * NFACT + f], 0.f);
    float qa2v = fmaxf(qn[16 + b] + nfof - 2.f * dots[(6 * 8 + b) * NFACT + f], 0.f);
    float cb = fmaxf(qn[b] + nfrf - 2.f * dots[(0 * 8 + b) * NFACT + f], 0.f) + qa1v + qa2v;
#pragma unroll
    for (int r = 0; r < 2; ++r) {
        float t1 = fmaxf(qn[24 + r * 8 + b] + nfrf - 2.f * dots[((1 + r) * 8 + b) * NFACT + f], 0.f);
        c1[(r * 8 + b) * NFACT + f] = t1 + qa1v;
        float t2 = fmaxf(qn[40 + r * 8 + b] + nfrf - 2.f * dots[((3 + r) * 8 + b) * NFACT + f], 0.f);
        qz[(r * 8 + b) * NFACT + f] = t2 + qa2v;
    }
    atomicMin(&sbase, __float_as_uint(cb));
    __syncthreads();
    if (threadIdx.x == 0) atomicMin((unsigned*)&base_min[b], sbase);
}

// ---------------- fused MFMA ent x fo GEMM + min-plus ------------------
// split-bf16 K=256. grid (32,16): 64 ent x 256 facts, sub-tiles of 64 f.
// 4 waves: wave w owns rows [w*16, w*16+16) x all 64 facts of sub-tile.
__global__ __launch_bounds__(256, 2) void k_minplus(
        const unsigned short* __restrict__ entb, const unsigned short* __restrict__ fob,
        const float* __restrict__ ne, const float* __restrict__ nfo,
        const float* __restrict__ c1, float* __restrict__ msum) {
    __shared__ unsigned short ent_l[64 * 264];    // 33792 B (pad 8: conflict-free b128)
    __shared__ unsigned short fo_l[64 * 264];     // 33792 B
    __shared__ float c_t[64 * 20];                // [f][br]
    __shared__ float ne_l[64];
    __shared__ float nfo_l[64];
    int tid = threadIdx.x;
    int lane = tid & 63, w = tid >> 6;
    int nb = blockIdx.x * 64;
    int f0 = blockIdx.y * 256;

    // stage ent rows (reg-staged, padded LDS)
    {
        const unsigned short* src = entb + nb * 256;
#pragma unroll
        for (int i = 0; i < 8; ++i) {
            int el = i * 2048 + tid * 8;          // ushort idx in [64][256]
            int row = el >> 8, k = el & 255;
            *(ushort4*)&ent_l[row * 264 + k] =
                *(const ushort4*)&src[el];
            *(ushort4*)&ent_l[row * 264 + k + 4] =
                *(const ushort4*)&src[el + 4];
        }
        if (tid < 64) ne_l[tid] = ne[nb + tid];
    }
    __syncthreads();

    float ne_reg[4];
#pragma unroll
    for (int q = 0; q < 4; ++q) ne_reg[q] = ne_l[w * 16 + (lane >> 4) * 4 + q];

    float minv[4][16];
#pragma unroll
    for (int q = 0; q < 4; ++q)
#pragma unroll
        for (int br = 0; br < 16; ++br) minv[q][br] = FLT_MAX;

    const unsigned short* ap_base = ent_l + (w * 16 + (lane & 15)) * 264 + (lane >> 4) * 8;
    const unsigned short* bp_base = fo_l + (lane & 15) * 264 + (lane >> 4) * 8;

    for (int ci = 0; ci < 4; ++ci) {
        int fb = f0 + ci * 64;
        __syncthreads();
        {
            const unsigned short* src = fob + fb * 256;
#pragma unroll
            for (int i = 0; i < 8; ++i) {
                int el = i * 2048 + tid * 8;
                int row = el >> 8, k = el & 255;
                *(ushort4*)&fo_l[row * 264 + k] = *(const ushort4*)&src[el];
                *(ushort4*)&fo_l[row * 264 + k + 4] = *(const ushort4*)&src[el + 4];
            }
            if (tid < 64) nfo_l[tid] = nfo[fb + tid];
            for (int p = tid; p < 1024; p += 256) {
                int f = p & 63, br = p >> 6;
                c_t[f * 20 + br] = c1[br * NFACT + fb + f];
            }
        }
        __syncthreads();

        f32x4 acc[4];
#pragma unroll
        for (int j = 0; j < 4; ++j) acc[j] = (f32x4)0.f;

#pragma unroll
        for (int step = 0; step < 8; ++step) {
            bf16x8 a = *(const bf16x8*)(ap_base + step * 32);
#pragma unroll
            for (int j = 0; j < 4; ++j) {
                bf16x8 b = *(const bf16x8*)(bp_base + j * 16 * 264 + step * 32);
                acc[j] = __builtin_amdgcn_mfma_f32_16x16x32_bf16(a, b, acc[j], 0, 0, 0);
            }
        }

        // epilogue: d = clamp(ne+nfo-2dot), min-plus into minv
#pragma unroll
        for (int j = 0; j < 4; ++j) {
            int f = j * 16 + (lane & 15);
            float s_nfo = nfo_l[f];
            const float* cr = &c_t[f * 20];
            float4 c0 = *(const float4*)(cr);
            float4 c4 = *(const float4*)(cr + 4);
            float4 c8 = *(const float4*)(cr + 8);
            float4 c12 = *(const float4*)(cr + 12);
#pragma unroll
            for (int q = 0; q < 4; ++q) {
                float d = fmaxf(ne_reg[q] + s_nfo - 2.f * acc[j][q], 0.f);
                minv[q][0] = fminf(minv[q][0], c0.x + d);
                minv[q][1] = fminf(minv[q][1], c0.y + d);
                minv[q][2] = fminf(minv[q][2], c0.z + d);
                minv[q][3] = fminf(minv[q][3], c0.w + d);
                minv[q][4] = fminf(minv[q][4], c4.x + d);
                minv[q][5] = fminf(minv[q][5], c4.y + d);
                minv[q][6] = fminf(minv[q][6], c4.z + d);
                minv[q][7] = fminf(minv[q][7], c4.w + d);
                minv[q][8] = fminf(minv[q][8], c8.x + d);
                minv[q][9] = fminf(minv[q][9], c8.y + d);
                minv[q][10] = fminf(minv[q][10], c8.z + d);
                minv[q][11] = fminf(minv[q][11], c8.w + d);
                minv[q][12] = fminf(minv[q][12], c12.x + d);
                minv[q][13] = fminf(minv[q][13], c12.y + d);
                minv[q][14] = fminf(minv[q][14], c12.z + d);
                minv[q][15] = fminf(minv[q][15], c12.w + d);
            }
        }
    }

    // butterfly-split reduce over the 16-lane f-group: lane keeps br = lane&15
    bool b3 = (lane & 8) != 0;
    float r8[4][8];
#pragma unroll
    for (int q = 0; q < 4; ++q)
#pragma unroll
        for (int j = 0; j < 8; ++j) {
            float a_ = minv[q][j], b_ = minv[q][j + 8];
            float keep = b3 ? b_ : a_;
            float send = b3 ? a_ : b_;
            r8[q][j] = fminf(keep, __shfl_xor(send, 8, 64));
        }
    bool b2 = (lane & 4) != 0;
    float r4[4][4];
#pragma unroll
    for (int q = 0; q < 4; ++q)
#pragma unroll
        for (int j = 0; j < 4; ++j) {
            float a_ = r8[q][j], b_ = r8[q][j + 4];
            float keep = b2 ? b_ : a_;
            float send = b2 ? a_ : b_;
            r4[q][j] = fminf(keep, __shfl_xor(send, 4, 64));
        }
    bool b1 = (lane & 2) != 0;
    float r2[4][2];
#pragma unroll
    for (int q = 0; q < 4; ++q)
#pragma unroll
        for (int j = 0; j < 2; ++j) {
            float a_ = r4[q][j], b_ = r4[q][j + 2];
            float keep = b1 ? b_ : a_;
            float send = b1 ? a_ : b_;
            r2[q][j] = fminf(keep, __shfl_xor(send, 2, 64));
        }
    bool b0 = (lane & 1) != 0;
    int nbase = nb + w * 16 + (lane >> 4) * 4;
    int brow = lane & 15;
#pragma unroll
    for (int q = 0; q < 4; ++q) {
        float a_ = r2[q][0], b_ = r2[q][1];
        float keep = b0 ? b_ : a_;
        float send = b0 ? a_ : b_;
        float v = fminf(keep, __shfl_xor(send, 1, 64));
        atomicMin((unsigned*)&msum[brow * NENT + nbase + q], __float_as_uint(v));
    }
}

// ---------------- top-10 smallest msum per (r,b) row (shuffle) ---------
__global__ void k_topk(const float* __restrict__ msum, int* __restrict__ z_idx,
                       float* __restrict__ z_msum) {
    __shared__ float sv[4];
    __shared__ int si[4];
    __shared__ float wv_;
    __shared__ int wi_;
    int br = blockIdx.x, t = threadIdx.x;
    float v[8];
#pragma unroll
    for (int p = 0; p < 8; ++p) v[p] = msum[br * NENT + t + 256 * p];
    for (int it = 0; it < KTOP; ++it) {
        float best = FLT_MAX;
        int bi = 1 << 30;
#pragma unroll
        for (int p = 0; p < 8; ++p) {
            int idx = t + 256 * p;
            if (v[p] < best) { best = v[p]; bi = idx; }
        }
#pragma unroll
        for (int m = 32; m; m >>= 1) {
            float ov = __shfl_xor(best, m, 64);
            int oi = __shfl_xor(bi, m, 64);
            if (ov < best || (ov == best && oi < bi)) { best = ov; bi = oi; }
        }
        int lane = t & 63, w = t >> 6;
        if (lane == 0) { sv[w] = best; si[w] = bi; }
        __syncthreads();
        if (t == 0) {
            float bb = sv[0]; int bj = si[0];
            for (int ww = 1; ww < 4; ++ww)
                if (sv[ww] < bb || (sv[ww] == bb && si[ww] < bj)) { bb = sv[ww]; bj = si[ww]; }
            z_idx[br * KTOP + it] = bj;
            z_msum[br * KTOP + it] = bb;
            wv_ = bb; wi_ = bj;
        }
        __syncthreads();
        int wi = wi_;
        if ((wi & 255) == t) {
            int p_ = wi >> 8;
#pragma unroll
            for (int p = 0; p < 8; ++p)
                if (p == p_) v[p] = FLT_MAX;
        }
        __syncthreads();
    }
}

// ---------------- z2: tiled GEMM-style min-plus over facts -------------
// grid (5, 32): 32 rows x 128 facts per block, inner tiles of 32.
__global__ __launch_bounds__(256) void k_z2(
        const float* __restrict__ ent, const float* __restrict__ fs,
        const float* __restrict__ nfs, const float* __restrict__ ne,
        const float* __restrict__ qz, const int* __restrict__ z_idx,
        float* __restrict__ z2sum) {
    __shared__ __align__(16) float z_l[32 * 132];
    __shared__ __align__(16) float fs_l[32 * 132];
    __shared__ float qz_l[32 * 33];
    __shared__ float nz_l[32];
    __shared__ float nfs_l[32];
    __shared__ float mred[32 * 17];
    int tid = threadIdx.x;
    int r0 = blockIdx.x * 32;
    int f0 = blockIdx.y * 128;

    for (int idx = tid; idx < 32 * 128; idx += 256) {
        int row = idx >> 7, col = idx & 127;
        z_l[row * 132 + col] = ent[z_idx[r0 + row] * EDIM + col];
    }
    if (tid < 32) nz_l[tid] = ne[z_idx[r0 + tid]];

    int ng = tid & 15, fg = tid >> 4;
    float m[2] = {FLT_MAX, FLT_MAX};

    for (int ci = 0; ci < 4; ++ci) {
        int fb = f0 + ci * 32;
        __syncthreads();
        for (int idx = tid; idx < 32 * 128; idx += 256) {
            int row = idx >> 7, col = idx & 127;
            fs_l[row * 132 + col] = fs[(fb + row) * EDIM + col];
        }
        if (tid < 32) nfs_l[tid] = nfs[fb + tid];
        for (int idx = tid; idx < 32 * 32; idx += 256) {
            int row = idx >> 5, col = idx & 31;
            int br = (r0 + row) / KTOP;
            qz_l[row * 33 + col] = qz[br * NFACT + fb + col];
        }
        __syncthreads();

        float acc[2][2] = {{0.f, 0.f}, {0.f, 0.f}};
#pragma unroll 4
        for (int es = 0; es < 32; ++es) {
            float4 bv0 = *(const float4*)&fs_l[fg * 132 + es * 4];
            float4 bv1 = *(const float4*)&fs_l[(fg + 16) * 132 + es * 4];
            float4 a0 = *(const float4*)&z_l[ng * 132 + es * 4];
            float4 a1 = *(const float4*)&z_l[(ng + 16) * 132 + es * 4];
            acc[0][0] += a0.x * bv0.x + a0.y * bv0.y + a0.z * bv0.z + a0.w * bv0.w;
            acc[0][1] += a0.x * bv1.x + a0.y * bv1.y + a0.z * bv1.z + a0.w * bv1.w;
            acc[1][0] += a1.x * bv0.x + a1.y * bv0.y + a1.z * bv0.z + a1.w * bv0.w;
            acc[1][1] += a1.x * bv1.x + a1.y * bv1.y + a1.z * bv1.z + a1.w * bv1.w;
        }
#pragma unroll
        for (int i = 0; i < 2; ++i)
#pragma unroll
            for (int j = 0; j < 2; ++j) {
                int row = ng + 16 * i, f = fg + 16 * j;
                float val = qz_l[row * 33 + f] +
                            fmaxf(nz_l[row] + nfs_l[f] - 2.f * acc[i][j], 0.f);
                m[i] = fminf(m[i], val);
            }
    }
    mred[ng * 17 + fg] = m[0];
    mred[(ng + 16) * 17 + fg] = m[1];
    __syncthreads();
    if (tid < 32) {
        float mm = FLT_MAX;
#pragma unroll
        for (int j = 0; j < 16; ++j) mm = fminf(mm, mred[tid * 17 + j]);
        atomicMin((unsigned*)&z2sum[r0 + tid], __float_as_uint(mm));
    }
}

// ---------------- final combine ----------------------------------------
__global__ void k_final(const float* __restrict__ base_min, const float* __restrict__ z_msum,
                        const float* __restrict__ z2sum, float* __restrict__ out) {
    int b = threadIdx.x;
    if (b >= BQ) return;
    float best = expf(-0.5f * base_min[b]);
#pragma unroll
    for (int r = 0; r < 2; ++r) {
        int br = r * 8 + b;
        float rb = 0.f;
        for (int k = 0; k < KTOP; ++k) {
            float s = expf(-0.5f * fmaxf(z2sum[br * KTOP + k], z_msum[br * KTOP + k]));
            rb = fmaxf(rb, s);
        }
        best = fmaxf(best, rb);
    }
    out[b] = best;
}

extern "C" void kernel_launch(void* const* d_in, const int* in_sizes, int n_in,
                              void* d_out, int out_size, void* d_ws, size_t ws_size,
                              hipStream_t stream) {
    const float* rel = (const float*)d_in[0];
    const float* arg1 = (const float*)d_in[1];
    const float* arg2 = (const float*)d_in[2];
    const float* fr = (const float*)d_in[3];
    const float* fs = (const float*)d_in[4];
    const float* fo = (const float*)d_in[5];
    const float* ent = (const float*)d_in[6];
    const float* W = (const float*)d_in[7];
    const float* bias = (const float*)d_in[8];
    float* out = (float*)d_out;

    float* w = (float*)d_ws;
    float* h = w;                          // 4096
    float* qn = h + 4096;                  // 64
    float* nfr = qn + 64;                  // 4096
    float* nfs = nfr + 4096;               // 4096
    float* nfo = nfs + 4096;               // 4096
    float* ne = nfo + 4096;                // 2048
    float* dots = ne + 2048;               // 229376
    float* c1 = dots + 229376;             // 65536
    float* qz = c1 + 65536;                // 65536
    float* msum = qz + 65536;              // 32768
    float* base_min = msum + 32768;        // 8
    float* z_msum = base_min + 8;          // 160
    float* z2sum = z_msum + 160;           // 160
    int* z_idx = (int*)(z2sum + 160);      // 160
    unsigned short* entb = (unsigned short*)(z_idx + 160);  // 2048*256 u16
    unsigned short* fob = entb + NENT * 256;                // 4096*256 u16

    k_prep<<<919, 256, 0, stream>>>(rel, arg1, arg2, W, bias, ent, fo,
                                    h, qn, ne, msum, base_min, z2sum, entb, fob);
    k_dots<<<112, 256, 0, stream>>>(rel, arg1, arg2, h, fr, fs, fo, dots, nfr, nfs, nfo);
    k_combine<<<128, 256, 0, stream>>>(dots, qn, nfr, nfs, nfo, c1, qz, base_min);
    k_minplus<<<dim3(32, 16), 256, 0, stream>>>(entb, fob, ne, nfo, c1, msum);
    k_topk<<<16, 256, 0, stream>>>(msum, z_idx, z_msum);
    k_z2<<<dim3(5, 32), 256, 0, stream>>>(ent, fs, nfs, ne, qz, z_idx, z2sum);
    k_final<<<1, 64, 0, stream>>>(base_min, z_msum, z2sum, out);
}

// Round 5
// 90.969 us; speedup vs baseline: 6.9153x; 1.0524x over previous
//
#include <hip/hip_runtime.h>
#include <hip/hip_bf16.h>
#include <float.h>

#define EDIM 128
#define NFACT 4096
#define NENT 2048
#define BQ 8
#define KTOP 10

typedef float f32x4 __attribute__((ext_vector_type(4)));
typedef __bf16 bf16x8 __attribute__((ext_vector_type(8)));

__device__ __forceinline__ float wave_sum(float v) {
#pragma unroll
    for (int m = 32; m; m >>= 1) v += __shfl_xor(v, m, 64);
    return v;
}

__device__ __forceinline__ unsigned short bfbits(float x) {
    __bf16 h = (__bf16)x;
    return __builtin_bit_cast(unsigned short, h);
}

// ---------------- prep: h+qnorm(h), qnorms, ne, inits, bf16-split conv -
// grid 1431 x 256
__global__ void k_prep(const float* __restrict__ rel, const float* __restrict__ a1,
                       const float* __restrict__ a2, const float* __restrict__ W,
                       const float* __restrict__ bias, const float* __restrict__ ent,
                       const float* __restrict__ fo, const float* __restrict__ fs,
                       float* __restrict__ h, float* __restrict__ qn,
                       float* __restrict__ ne, float* __restrict__ msum,
                       float* __restrict__ base_min, float* __restrict__ z2sum,
                       unsigned short* __restrict__ entb, unsigned short* __restrict__ fob,
                       unsigned short* __restrict__ fsb) {
    int blk = blockIdx.x;
    int tid = threadIdx.x;
    if (blk < 16) {
        __shared__ float s_[4];
        int row = blk * 2 + (tid >> 7);        // 0..31 = (r*2+jj)*8+b
        int e = tid & 127;
        int b = row & 7, rj = row >> 3;
        const float* Wp = W + rj * EDIM * EDIM;
        float acc = bias[rj * EDIM + e];
        for (int k = 0; k < EDIM; ++k)
            acc += rel[b * EDIM + k] * Wp[k * EDIM + e];
        h[row * EDIM + e] = acc;
        float p = wave_sum(acc * acc);
        if ((tid & 63) == 0) s_[tid >> 6] = p;
        __syncthreads();
        if ((tid & 127) == 0) {
            int half = tid >> 7;
            float nn = s_[half * 2] + s_[half * 2 + 1];
            int jj = (row >> 3) & 1, r = row >> 4, bb = row & 7;
            qn[24 + jj * 16 + r * 8 + bb] = nn;
        }
    } else if (blk < 22) {
        int j = (blk - 16) * 4 + (tid >> 6);
        int l = tid & 63;
        if (j < 24) {
            const float* v = (j < 8) ? rel + j * EDIM
                           : (j < 16) ? a1 + (j - 8) * EDIM : a2 + (j - 16) * EDIM;
            float p = wave_sum(v[l] * v[l] + v[l + 64] * v[l + 64]);
            if (l == 0) qn[j] = p;
        }
    } else if (blk < 86) {
        int base = (blk - 22) * 32;
        int lane = tid & 63, wv = tid >> 6;
        for (int rr = wv; rr < 32; rr += 4) {
            int n = base + rr;
            float a = ent[n * EDIM + lane], b2 = ent[n * EDIM + lane + 64];
            float p = wave_sum(a * a + b2 * b2);
            if (lane == 0) ne[n] = p;
        }
    } else if (blk < 150) {
        int i = (blk - 86) * 512 + tid;
        msum[i] = FLT_MAX;
        msum[i + 256] = FLT_MAX;
    } else if (blk == 150) {
        if (tid < BQ) base_min[tid] = FLT_MAX;
        if (tid < 160) z2sum[tid] = FLT_MAX;
    } else {
        // split-bf16 conversion: 10240 rows (2048 ent + 4096 fo + 4096 fs) x 128
        int idx = (blk - 151) * 1024 + tid * 4;
        int row = idx >> 7, col = idx & 127;
        const float* src;
        unsigned short* dst;
        if (row < NENT) { src = ent + row * EDIM + col; dst = entb + row * 256; }
        else if (row < NENT + NFACT) { src = fo + (row - NENT) * EDIM + col; dst = fob + (row - NENT) * 256; }
        else { src = fs + (row - NENT - NFACT) * EDIM + col; dst = fsb + (row - NENT - NFACT) * 256; }
        float4 x = *(const float4*)src;
        ushort4 hv, lv;
        hv.x = bfbits(x.x); hv.y = bfbits(x.y); hv.z = bfbits(x.z); hv.w = bfbits(x.w);
        lv.x = bfbits(x.x - (float)(__bf16)x.x);
        lv.y = bfbits(x.y - (float)(__bf16)x.y);
        lv.z = bfbits(x.z - (float)(__bf16)x.z);
        lv.w = bfbits(x.w - (float)(__bf16)x.w);
        *(ushort4*)(dst + col) = hv;
        *(ushort4*)(dst + 128 + col) = lv;
    }
}

// ---------------- dots: 7 groups of 8 query rows vs facts --------------
__global__ void k_dots(const float* __restrict__ rel, const float* __restrict__ a1,
                       const float* __restrict__ a2, const float* __restrict__ h,
                       const float* __restrict__ fr, const float* __restrict__ fs,
                       const float* __restrict__ fo, float* __restrict__ dots,
                       float* __restrict__ nfr, float* __restrict__ nfs,
                       float* __restrict__ nfo) {
    __shared__ __align__(16) float q[128 * 64];   // [e][j], j padded to 64
    for (int idx = threadIdx.x; idx < 128 * 64; idx += 256) {
        int e = idx >> 6, j = idx & 63;
        float v = 0.f;
        if (j < 56) {
            if (j < 8) v = rel[j * 128 + e];
            else if (j < 16) v = a1[(j - 8) * 128 + e];
            else if (j < 24) v = a2[(j - 16) * 128 + e];
            else {
                int t2 = j - 24;
                int jj = t2 >> 4, r = (t2 >> 3) & 1, bb = t2 & 7;
                v = h[((r * 2 + jj) * 8 + bb) * 128 + e];
            }
        }
        q[idx] = v;
    }
    __syncthreads();

    int tg = blockIdx.x * 256 + threadIdx.x;      // 0..28671
    int f = tg & (NFACT - 1);
    int g = tg >> 12;                             // 0..6
    const float* rowp = ((g < 5) ? fr : (g == 5 ? fs : fo)) + f * EDIM;
    const int qbase_tab[7] = {0, 24, 32, 40, 48, 8, 16};
    int qb = qbase_tab[g];

    float acc[8] = {0, 0, 0, 0, 0, 0, 0, 0};
    float nrm = 0.f;
    const float4* rp4 = (const float4*)rowp;
#pragma unroll 4
    for (int es = 0; es < 32; ++es) {
        float4 x = rp4[es];
        float xs[4] = {x.x, x.y, x.z, x.w};
        nrm += x.x * x.x + x.y * x.y + x.z * x.z + x.w * x.w;
#pragma unroll
        for (int c = 0; c < 4; ++c) {
            int e = es * 4 + c;
            float xe = xs[c];
            float4 q0 = *(const float4*)&q[e * 64 + qb];
            float4 q1 = *(const float4*)&q[e * 64 + qb + 4];
            acc[0] += xe * q0.x; acc[1] += xe * q0.y;
            acc[2] += xe * q0.z; acc[3] += xe * q0.w;
            acc[4] += xe * q1.x; acc[5] += xe * q1.y;
            acc[6] += xe * q1.z; acc[7] += xe * q1.w;
        }
    }
#pragma unroll
    for (int j = 0; j < 8; ++j) dots[(g * 8 + j) * NFACT + f] = acc[j];
    if (g == 0) nfr[f] = nrm;
    else if (g == 5) nfs[f] = nrm;
    else if (g == 6) nfo[f] = nrm;
}

// ---------------- combine dots -> c1, qz, base_min ---------------------
__global__ void k_combine(const float* __restrict__ dots, const float* __restrict__ qn,
                          const float* __restrict__ nfr, const float* __restrict__ nfs,
                          const float* __restrict__ nfo, float* __restrict__ c1,
                          float* __restrict__ qz, float* __restrict__ base_min) {
    __shared__ unsigned sbase;
    if (threadIdx.x == 0) sbase = 0x7f7fffffu;
    __syncthreads();
    int gid = blockIdx.x * 256 + threadIdx.x;     // 0..32767
    int b = gid >> 12;
    int f = gid & (NFACT - 1);
    float nfrf = nfr[f], nfsf = nfs[f], nfof = nfo[f];
    float qa1v = fmaxf(qn[8 + b] + nfsf - 2.f * dots[(5 * 8 + b) * NFACT + f], 0.f);
    float qa2v = fmaxf(qn[16 + b] + nfof - 2.f * dots[(6 * 8 + b) * NFACT + f], 0.f);
    float cb = fmaxf(qn[b] + nfrf - 2.f * dots[(0 * 8 + b) * NFACT + f], 0.f) + qa1v + qa2v;
#pragma unroll
    for (int r = 0; r < 2; ++r) {
        float t1 = fmaxf(qn[24 + r * 8 + b] + nfrf - 2.f * dots[((1 + r) * 8 + b) * NFACT + f], 0.f);
        c1[(r * 8 + b) * NFACT + f] = t1 + qa1v;
        float t2 = fmaxf(qn[40 + r * 8 + b] + nfrf - 2.f * dots[((3 + r) * 8 + b) * NFACT + f], 0.f);
        qz[(r * 8 + b) * NFACT + f] = t2 + qa2v;
    }
    atomicMin(&sbase, __float_as_uint(cb));
    __syncthreads();
    if (threadIdx.x == 0) atomicMin((unsigned*)&base_min[b], sbase);
}

// ---------------- fused MFMA ent x fo GEMM + min-plus ------------------
// split-bf16 K=256. grid (32,16): 64 ent x 256 facts, sub-tiles of 64 f.
__global__ __launch_bounds__(256, 2) void k_minplus(
        const unsigned short* __restrict__ entb, const unsigned short* __restrict__ fob,
        const float* __restrict__ ne, const float* __restrict__ nfo,
        const float* __restrict__ c1, float* __restrict__ msum) {
    __shared__ unsigned short ent_l[64 * 264];    // pad 8: conflict-free b128
    __shared__ unsigned short fo_l[64 * 264];
    __shared__ float c_t[64 * 20];                // [f][br]
    __shared__ float ne_l[64];
    __shared__ float nfo_l[64];
    int tid = threadIdx.x;
    int lane = tid & 63, w = tid >> 6;
    int nb = blockIdx.x * 64;
    int f0 = blockIdx.y * 256;

    {
        const unsigned short* src = entb + nb * 256;
#pragma unroll
        for (int i = 0; i < 8; ++i) {
            int el = i * 2048 + tid * 8;          // ushort idx in [64][256]
            int row = el >> 8, k = el & 255;
            *(uint4*)&ent_l[row * 264 + k] = *(const uint4*)&src[el];
        }
        if (tid < 64) ne_l[tid] = ne[nb + tid];
    }
    __syncthreads();

    float ne_reg[4];
#pragma unroll
    for (int q = 0; q < 4; ++q) ne_reg[q] = ne_l[w * 16 + (lane >> 4) * 4 + q];

    float minv[4][16];
#pragma unroll
    for (int q = 0; q < 4; ++q)
#pragma unroll
        for (int br = 0; br < 16; ++br) minv[q][br] = FLT_MAX;

    const unsigned short* ap_base = ent_l + (w * 16 + (lane & 15)) * 264 + (lane >> 4) * 8;
    const unsigned short* bp_base = fo_l + (lane & 15) * 264 + (lane >> 4) * 8;

    for (int ci = 0; ci < 4; ++ci) {
        int fb = f0 + ci * 64;
        __syncthreads();
        {
            const unsigned short* src = fob + fb * 256;
#pragma unroll
            for (int i = 0; i < 8; ++i) {
                int el = i * 2048 + tid * 8;
                int row = el >> 8, k = el & 255;
                *(uint4*)&fo_l[row * 264 + k] = *(const uint4*)&src[el];
            }
            if (tid < 64) nfo_l[tid] = nfo[fb + tid];
            for (int p = tid; p < 1024; p += 256) {
                int f = p & 63, br = p >> 6;
                c_t[f * 20 + br] = c1[br * NFACT + fb + f];
            }
        }
        __syncthreads();

        f32x4 acc[4];
#pragma unroll
        for (int j = 0; j < 4; ++j) acc[j] = (f32x4)0.f;

#pragma unroll
        for (int step = 0; step < 8; ++step) {
            bf16x8 a = *(const bf16x8*)(ap_base + step * 32);
#pragma unroll
            for (int j = 0; j < 4; ++j) {
                bf16x8 b = *(const bf16x8*)(bp_base + j * 16 * 264 + step * 32);
                acc[j] = __builtin_amdgcn_mfma_f32_16x16x32_bf16(a, b, acc[j], 0, 0, 0);
            }
        }

#pragma unroll
        for (int j = 0; j < 4; ++j) {
            int f = j * 16 + (lane & 15);
            float s_nfo = nfo_l[f];
            const float* cr = &c_t[f * 20];
            float4 c0 = *(const float4*)(cr);
            float4 c4 = *(const float4*)(cr + 4);
            float4 c8 = *(const float4*)(cr + 8);
            float4 c12 = *(const float4*)(cr + 12);
#pragma unroll
            for (int q = 0; q < 4; ++q) {
                float d = fmaxf(ne_reg[q] + s_nfo - 2.f * acc[j][q], 0.f);
                minv[q][0] = fminf(minv[q][0], c0.x + d);
                minv[q][1] = fminf(minv[q][1], c0.y + d);
                minv[q][2] = fminf(minv[q][2], c0.z + d);
                minv[q][3] = fminf(minv[q][3], c0.w + d);
                minv[q][4] = fminf(minv[q][4], c4.x + d);
                minv[q][5] = fminf(minv[q][5], c4.y + d);
                minv[q][6] = fminf(minv[q][6], c4.z + d);
                minv[q][7] = fminf(minv[q][7], c4.w + d);
                minv[q][8] = fminf(minv[q][8], c8.x + d);
                minv[q][9] = fminf(minv[q][9], c8.y + d);
                minv[q][10] = fminf(minv[q][10], c8.z + d);
                minv[q][11] = fminf(minv[q][11], c8.w + d);
                minv[q][12] = fminf(minv[q][12], c12.x + d);
                minv[q][13] = fminf(minv[q][13], c12.y + d);
                minv[q][14] = fminf(minv[q][14], c12.z + d);
                minv[q][15] = fminf(minv[q][15], c12.w + d);
            }
        }
    }

    // butterfly-split reduce over the 16-lane f-group: lane keeps br = lane&15
    bool b3 = (lane & 8) != 0;
    float r8[4][8];
#pragma unroll
    for (int q = 0; q < 4; ++q)
#pragma unroll
        for (int j = 0; j < 8; ++j) {
            float a_ = minv[q][j], b_ = minv[q][j + 8];
            float keep = b3 ? b_ : a_;
            float send = b3 ? a_ : b_;
            r8[q][j] = fminf(keep, __shfl_xor(send, 8, 64));
        }
    bool b2 = (lane & 4) != 0;
    float r4[4][4];
#pragma unroll
    for (int q = 0; q < 4; ++q)
#pragma unroll
        for (int j = 0; j < 4; ++j) {
            float a_ = r8[q][j], b_ = r8[q][j + 4];
            float keep = b2 ? b_ : a_;
            float send = b2 ? a_ : b_;
            r4[q][j] = fminf(keep, __shfl_xor(send, 4, 64));
        }
    bool b1 = (lane & 2) != 0;
    float r2[4][2];
#pragma unroll
    for (int q = 0; q < 4; ++q)
#pragma unroll
        for (int j = 0; j < 2; ++j) {
            float a_ = r4[q][j], b_ = r4[q][j + 2];
            float keep = b1 ? b_ : a_;
            float send = b1 ? a_ : b_;
            r2[q][j] = fminf(keep, __shfl_xor(send, 2, 64));
        }
    bool b0 = (lane & 1) != 0;
    int nbase = nb + w * 16 + (lane >> 4) * 4;
    int brow = lane & 15;
#pragma unroll
    for (int q = 0; q < 4; ++q) {
        float a_ = r2[q][0], b_ = r2[q][1];
        float keep = b0 ? b_ : a_;
        float send = b0 ? a_ : b_;
        float v = fminf(keep, __shfl_xor(send, 1, 64));
        atomicMin((unsigned*)&msum[brow * NENT + nbase + q], __float_as_uint(v));
    }
}

// ---------------- top-10 smallest msum per (r,b) row -------------------
// phase 1: each wave extracts local top-10 over its 512 elems (no sync);
// phase 2: wave 0 merges 40 candidates.
__global__ void k_topk(const float* __restrict__ msum, int* __restrict__ z_idx,
                       float* __restrict__ z_msum) {
    __shared__ float candv[40];
    __shared__ int candi[40];
    int br = blockIdx.x, t = threadIdx.x;
    int lane = t & 63, w = t >> 6;
    float v[8];
#pragma unroll
    for (int p = 0; p < 8; ++p) v[p] = msum[br * NENT + w * 512 + p * 64 + lane];
    for (int it = 0; it < KTOP; ++it) {
        float best = FLT_MAX;
        int bi = 0x7fffffff;
#pragma unroll
        for (int p = 0; p < 8; ++p) {
            if (v[p] < best) { best = v[p]; bi = w * 512 + p * 64 + lane; }
        }
#pragma unroll
        for (int m = 32; m; m >>= 1) {
            float ov = __shfl_xor(best, m, 64);
            int oi = __shfl_xor(bi, m, 64);
            if (ov < best || (ov == best && oi < bi)) { best = ov; bi = oi; }
        }
        if (lane == 0) { candv[w * KTOP + it] = best; candi[w * KTOP + it] = bi; }
        if ((bi & 63) == lane) {
            int p_ = (bi >> 6) & 7;
#pragma unroll
            for (int p = 0; p < 8; ++p)
                if (p == p_) v[p] = FLT_MAX;
        }
    }
    __syncthreads();
    if (w == 0) {
        float mv = (lane < 40) ? candv[lane] : FLT_MAX;
        int mi = (lane < 40) ? candi[lane] : 0x7fffffff;
        for (int it = 0; it < KTOP; ++it) {
            float best = mv;
            int bi = mi;
#pragma unroll
            for (int m = 32; m; m >>= 1) {
                float ov = __shfl_xor(best, m, 64);
                int oi = __shfl_xor(bi, m, 64);
                if (ov < best || (ov == best && oi < bi)) { best = ov; bi = oi; }
            }
            if (lane == 0) {
                z_idx[br * KTOP + it] = bi;
                z_msum[br * KTOP + it] = best;
            }
            if (bi == mi) mv = FLT_MAX;
        }
    }
}

// ---------------- z2: MFMA split-bf16 min-plus over facts --------------
// grid (5,16): 32 z-rows x 256 facts per block, sub-tiles of 64 facts.
__global__ __launch_bounds__(256) void k_z2(
        const unsigned short* __restrict__ entb, const unsigned short* __restrict__ fsb,
        const float* __restrict__ nfs, const float* __restrict__ ne,
        const float* __restrict__ qz, const int* __restrict__ z_idx,
        float* __restrict__ z2sum) {
    __shared__ unsigned short zb_l[32 * 264];
    __shared__ unsigned short fs_l[64 * 264];
    __shared__ float qz_l[64 * 33];               // [f][row]
    __shared__ float nz_l[32];
    __shared__ float nfs_l[64];
    __shared__ int zrow_l[32];
    __shared__ int brow_l[32];
    int tid = threadIdx.x;
    int lane = tid & 63, w = tid >> 6;
    int r0 = blockIdx.x * 32;
    int f0 = blockIdx.y * 256;

    if (tid < 32) {
        int zi = z_idx[r0 + tid];
        zrow_l[tid] = zi;
        nz_l[tid] = ne[zi];
        brow_l[tid] = (r0 + tid) / KTOP;
    }
    __syncthreads();
    for (int p = tid; p < 1024; p += 256) {
        int row = p >> 5, k = (p & 31) * 8;
        *(uint4*)&zb_l[row * 264 + k] = *(const uint4*)&entb[zrow_l[row] * 256 + k];
    }

    int rw = w & 1, fh = w >> 1;
    const unsigned short* ap_base = zb_l + (rw * 16 + (lane & 15)) * 264 + (lane >> 4) * 8;
    const unsigned short* bp_base = fs_l + (lane & 15) * 264 + (lane >> 4) * 8;

    float nz_reg[4];
    float m[4];
#pragma unroll
    for (int q = 0; q < 4; ++q) m[q] = FLT_MAX;

    for (int ci = 0; ci < 4; ++ci) {
        int fb = f0 + ci * 64;
        __syncthreads();
        for (int p = tid; p < 2048; p += 256) {
            int row = p >> 5, k = (p & 31) * 8;
            *(uint4*)&fs_l[row * 264 + k] = *(const uint4*)&fsb[(fb + row) * 256 + k];
        }
        if (tid < 64) nfs_l[tid] = nfs[fb + tid];
        for (int p = tid; p < 2048; p += 256) {
            int row = p >> 6, f = p & 63;
            qz_l[f * 33 + row] = qz[brow_l[row] * NFACT + fb + f];
        }
        __syncthreads();
        if (ci == 0) {
#pragma unroll
            for (int q = 0; q < 4; ++q)
                nz_reg[q] = nz_l[rw * 16 + (lane >> 4) * 4 + q];
        }

        f32x4 acc[2];
        acc[0] = (f32x4)0.f;
        acc[1] = (f32x4)0.f;
#pragma unroll
        for (int step = 0; step < 8; ++step) {
            bf16x8 a = *(const bf16x8*)(ap_base + step * 32);
#pragma unroll
            for (int j = 0; j < 2; ++j) {
                bf16x8 b = *(const bf16x8*)(bp_base + (fh * 2 + j) * 16 * 264 + step * 32);
                acc[j] = __builtin_amdgcn_mfma_f32_16x16x32_bf16(a, b, acc[j], 0, 0, 0);
            }
        }

#pragma unroll
        for (int j = 0; j < 2; ++j) {
            int f = (fh * 2 + j) * 16 + (lane & 15);
            float s_nfs = nfs_l[f];
            const float* qzr = &qz_l[f * 33 + rw * 16 + (lane >> 4) * 4];
#pragma unroll
            for (int q = 0; q < 4; ++q) {
                float d = fmaxf(nz_reg[q] + s_nfs - 2.f * acc[j][q], 0.f);
                m[q] = fminf(m[q], qzr[q] + d);
            }
        }
    }
    // reduce m[q] across the 16 lanes of each f-group
#pragma unroll
    for (int q = 0; q < 4; ++q) {
        float v = m[q];
        v = fminf(v, __shfl_xor(v, 1, 64));
        v = fminf(v, __shfl_xor(v, 2, 64));
        v = fminf(v, __shfl_xor(v, 4, 64));
        v = fminf(v, __shfl_xor(v, 8, 64));
        if ((lane & 15) == 0) {
            int row = rw * 16 + (lane >> 4) * 4 + q;
            atomicMin((unsigned*)&z2sum[r0 + row], __float_as_uint(v));
        }
    }
}

// ---------------- final combine ----------------------------------------
__global__ void k_final(const float* __restrict__ base_min, const float* __restrict__ z_msum,
                        const float* __restrict__ z2sum, float* __restrict__ out) {
    int b = threadIdx.x;
    if (b >= BQ) return;
    float best = expf(-0.5f * base_min[b]);
#pragma unroll
    for (int r = 0; r < 2; ++r) {
        int br = r * 8 + b;
        float rb = 0.f;
        for (int k = 0; k < KTOP; ++k) {
            float s = expf(-0.5f * fmaxf(z2sum[br * KTOP + k], z_msum[br * KTOP + k]));
            rb = fmaxf(rb, s);
        }
        best = fmaxf(best, rb);
    }
    out[b] = best;
}

extern "C" void kernel_launch(void* const* d_in, const int* in_sizes, int n_in,
                              void* d_out, int out_size, void* d_ws, size_t ws_size,
                              hipStream_t stream) {
    const float* rel = (const float*)d_in[0];
    const float* arg1 = (const float*)d_in[1];
    const float* arg2 = (const float*)d_in[2];
    const float* fr = (const float*)d_in[3];
    const float* fs = (const float*)d_in[4];
    const float* fo = (const float*)d_in[5];
    const float* ent = (const float*)d_in[6];
    const float* W = (const float*)d_in[7];
    const float* bias = (const float*)d_in[8];
    float* out = (float*)d_out;

    float* w = (float*)d_ws;
    float* h = w;                          // 4096
    float* qn = h + 4096;                  // 64
    float* nfr = qn + 64;                  // 4096
    float* nfs = nfr + 4096;               // 4096
    float* nfo = nfs + 4096;               // 4096
    float* ne = nfo + 4096;                // 2048
    float* dots = ne + 2048;               // 229376
    float* c1 = dots + 229376;             // 65536
    float* qz = c1 + 65536;                // 65536
    float* msum = qz + 65536;              // 32768
    float* base_min = msum + 32768;        // 8
    float* z_msum = base_min + 8;          // 160
    float* z2sum = z_msum + 160;           // 160
    int* z_idx = (int*)(z2sum + 160);      // 160
    unsigned short* entb = (unsigned short*)(z_idx + 160);  // 2048*256 u16
    unsigned short* fob = entb + NENT * 256;                // 4096*256 u16
    unsigned short* fsb = fob + NFACT * 256;                // 4096*256 u16

    k_prep<<<1431, 256, 0, stream>>>(rel, arg1, arg2, W, bias, ent, fo, fs,
                                     h, qn, ne, msum, base_min, z2sum, entb, fob, fsb);
    k_dots<<<112, 256, 0, stream>>>(rel, arg1, arg2, h, fr, fs, fo, dots, nfr, nfs, nfo);
    k_combine<<<128, 256, 0, stream>>>(dots, qn, nfr, nfs, nfo, c1, qz, base_min);
    k_minplus<<<dim3(32, 16), 256, 0, stream>>>(entb, fob, ne, nfo, c1, msum);
    k_topk<<<16, 256, 0, stream>>>(msum, z_idx, z_msum);
    k_z2<<<dim3(5, 16), 256, 0, stream>>>(entb, fsb, nfs, ne, qz, z_idx, z2sum);
    k_final<<<1, 64, 0, stream>>>(base_min, z_msum, z2sum, out);
}